// Round 2
// baseline (79713.129 us; speedup 1.0000x reference)
//
#include <hip/hip_runtime.h>
#include <hip/hip_bf16.h>
#include <stdint.h>

#define B  64
#define TD 512
#define TE 1024
#define EE 512
#define UU 256

// ---------- numeric helpers ----------
__device__ __forceinline__ float fexp2(float x){ return __builtin_amdgcn_exp2f(x); }
__device__ __forceinline__ float frcp_(float x){ return __builtin_amdgcn_rcpf(x); }
__device__ __forceinline__ float tanh_fast(float x){
  float e = fexp2(x * 2.885390082f);
  return 1.f - 2.f * frcp_(e + 1.f);
}
__device__ __forceinline__ float sigmoid_fast(float x){
  return frcp_(1.f + fexp2(-1.442695041f * x));
}
__device__ __forceinline__ unsigned short f2bf(float f){
  unsigned int u = __float_as_uint(f);
  u = (u + 0x7fffu + ((u >> 16) & 1u)) >> 16;   // RNE
  return (unsigned short)u;
}
__device__ __forceinline__ float bflo(unsigned int w){ return __uint_as_float(w << 16); }
__device__ __forceinline__ float bfhi(unsigned int w){ return __uint_as_float(w & 0xffff0000u); }

// Cross-XCD comm WITHOUT cache flushes: relaxed system-scope ops lower to
// global_load/store/atomic with sc0 sc1 (bypass L1/L2, coherent at L3) and
// never emit buffer_inv/buffer_wbl2 -> L2 stays hot for speech/KR.
__device__ __forceinline__ void gstore(float* p, float v){
  __hip_atomic_store(p, v, __ATOMIC_RELAXED, __HIP_MEMORY_SCOPE_SYSTEM);
}
__device__ __forceinline__ float gload(const float* p){
  return __hip_atomic_load(p, __ATOMIC_RELAXED, __HIP_MEMORY_SCOPE_SYSTEM);
}
__device__ __forceinline__ void drain_stores(){
  __atomic_signal_fence(__ATOMIC_SEQ_CST);
  __builtin_amdgcn_s_waitcnt(0);
  __atomic_signal_fence(__ATOMIC_SEQ_CST);
}

// Gate partial GEMV over k-range [k0, k0+32*NITER) of this WG's KRP slice,
// accumulating into LDS zb[256] (jj = (tid&31)*8 + i). Used for the x-rows
// (k0=0, runs one timestep EARLY to hide barrier B) and h-rows (k0=768,
// runs between barrier-A signal and poll to hide barrier A).
template<int NITER>
__device__ __forceinline__ void gate_accum(const unsigned short* __restrict__ KRP,
    const float* catp, float* zb, int q, int k0, int tid, int lane){
  const int c = tid & 31, kg = tid >> 5;
  const uint4* kp = (const uint4*)KRP + ((size_t)q*1024 + k0 + kg*NITER)*32 + c;
  float a0=0.f,a1=0.f,a2=0.f,a3=0.f,a4=0.f,a5=0.f,a6=0.f,a7=0.f;
  #pragma unroll 4
  for (int i = 0; i < NITER; ++i){
    uint4 w = kp[(size_t)i*32];
    float ck = catp[k0 + kg*NITER + i];
    a0 += ck*bflo(w.x); a1 += ck*bfhi(w.x);
    a2 += ck*bflo(w.y); a3 += ck*bfhi(w.y);
    a4 += ck*bflo(w.z); a5 += ck*bfhi(w.z);
    a6 += ck*bflo(w.w); a7 += ck*bfhi(w.w);
  }
  a0 += __shfl_xor(a0, 32); a1 += __shfl_xor(a1, 32);
  a2 += __shfl_xor(a2, 32); a3 += __shfl_xor(a3, 32);
  a4 += __shfl_xor(a4, 32); a5 += __shfl_xor(a5, 32);
  a6 += __shfl_xor(a6, 32); a7 += __shfl_xor(a7, 32);
  if (lane < 32){
    atomicAdd(&zb[c*8+0], a0); atomicAdd(&zb[c*8+1], a1);
    atomicAdd(&zb[c*8+2], a2); atomicAdd(&zb[c*8+3], a3);
    atomicAdd(&zb[c*8+4], a4); atomicAdd(&zb[c*8+5], a5);
    atomicAdd(&zb[c*8+6], a6); atomicAdd(&zb[c*8+7], a7);
  }
}

// ---------- pack kernels ----------
__global__ void pack_bf16v(const float* __restrict__ in, unsigned short* __restrict__ out, int n4){
  int i = blockIdx.x * blockDim.x + threadIdx.x;
  int stride = gridDim.x * blockDim.x;
  for (; i < n4; i += stride){
    float4 v = ((const float4*)in)[i];
    ushort4 o;
    o.x = f2bf(v.x); o.y = f2bf(v.y); o.z = f2bf(v.z); o.w = f2bf(v.w);
    ((ushort4*)out)[i] = o;
  }
}

// KRP[q][k][jj]: per-WG-contiguous gate weights. jj in [0,256) maps to
// logical column J = (jj>>6)*256 + q*64 + (jj&63); rows 0..767 = K, 768..1023 = R.
// Total elements = 4*1024*256 = 1,048,576 -> grid MUST be 4096 x 256 (R4 bug: 8192
// overran the 2 MB buffer and trashed Wab/x1).
__global__ void pack_KRP(const float* __restrict__ K, const float* __restrict__ R,
                         unsigned short* __restrict__ KRP){
  int idx = blockIdx.x * 256 + threadIdx.x;    // 4096 blocks -> 1M exactly
  int q  = idx >> 18;
  int k  = (idx >> 8) & 1023;
  int jj = idx & 255;
  int J  = (jj >> 6)*256 + q*64 + (jj & 63);
  float v = (k < 768) ? K[(size_t)k*1024 + J] : R[(size_t)(k - 768)*1024 + J];
  KRP[idx] = f2bf(v);
}

// ---------- secrets = trans @ emb_W + emb_b : [32768,64]@[64,256] ----------
__global__ __launch_bounds__(256) void emb_gemm(const float* __restrict__ trans,
    const float* __restrict__ W, const float* __restrict__ bias, float* __restrict__ out){
  __shared__ __align__(16) float aT[64*20];
  const int row0 = blockIdx.x * 16;
  const int tid = threadIdx.x;
  {
    int r = tid >> 6, k = tid & 63;
    for (int rr = r; rr < 16; rr += 4)
      aT[k*20 + rr] = trans[(size_t)(row0 + rr)*64 + k];
  }
  __syncthreads();
  const int j = tid;
  float bj = bias[j];
  float acc[16];
  #pragma unroll
  for (int r = 0; r < 16; ++r) acc[r] = bj;
  for (int k = 0; k < 64; ++k){
    float w = W[(size_t)k*UU + j];
    const float4* a4 = (const float4*)(aT + k*20);
    float4 q0 = a4[0], q1 = a4[1], q2 = a4[2], q3 = a4[3];
    acc[0]+=q0.x*w;  acc[1]+=q0.y*w;  acc[2]+=q0.z*w;  acc[3]+=q0.w*w;
    acc[4]+=q1.x*w;  acc[5]+=q1.y*w;  acc[6]+=q1.z*w;  acc[7]+=q1.w*w;
    acc[8]+=q2.x*w;  acc[9]+=q2.y*w;  acc[10]+=q2.z*w; acc[11]+=q2.w*w;
    acc[12]+=q3.x*w; acc[13]+=q3.y*w; acc[14]+=q3.z*w; acc[15]+=q3.w*w;
  }
  #pragma unroll
  for (int r = 0; r < 16; ++r)
    out[(size_t)(row0 + r)*UU + j] = acc[r];
}

// ---------- enc = speech @ Ua + Ua_b, stored bf16 [B][TE][U] ----------
__global__ __launch_bounds__(256) void enc_gemm(const float* __restrict__ speech,
    const float* __restrict__ Ua, const float* __restrict__ Uab,
    unsigned short* __restrict__ enc){
  __shared__ __align__(16) float aT[512*20];
  const int wg = blockIdx.x;
  const int b = wg >> 6, tb = (wg & 63) * 16;
  const int tid = threadIdx.x;
  const float* sp = speech + ((size_t)b*TE + tb)*EE;
  for (int it = 0; it < 32; ++it){
    int idx = tid + 256*it;
    int te = idx >> 9, e = idx & 511;
    aT[e*20 + te] = sp[(size_t)te*EE + e];
  }
  __syncthreads();
  const int j = tid;
  float bj = Uab[j];
  float acc[16];
  #pragma unroll
  for (int r = 0; r < 16; ++r) acc[r] = bj;
  const float* up = Ua + j;
  for (int e = 0; e < 512; ++e){
    float w = up[(size_t)e*UU];
    const float4* a4 = (const float4*)(aT + e*20);
    float4 q0 = a4[0], q1 = a4[1], q2 = a4[2], q3 = a4[3];
    acc[0]+=q0.x*w;  acc[1]+=q0.y*w;  acc[2]+=q0.z*w;  acc[3]+=q0.w*w;
    acc[4]+=q1.x*w;  acc[5]+=q1.y*w;  acc[6]+=q1.z*w;  acc[7]+=q1.w*w;
    acc[8]+=q2.x*w;  acc[9]+=q2.y*w;  acc[10]+=q2.z*w; acc[11]+=q2.w*w;
    acc[12]+=q3.x*w; acc[13]+=q3.y*w; acc[14]+=q3.z*w; acc[15]+=q3.w*w;
  }
  unsigned short* op = enc + ((size_t)b*TE + tb)*UU + j;
  #pragma unroll
  for (int r = 0; r < 16; ++r) op[(size_t)r*UU] = f2bf(acc[r]);
}

// ---------- persistent attention-LSTM scan ----------
// grid 256 = 64 batches x 4 WGs; 1024 threads. enc slice persisted in dynamic
// LDS (132 KB, stride 264 ushorts). All big streams are uint4 rolled loops.
// 4-WG barriers: relaxed system-scope counter (no cache flushes).
//
// R5 restructure (latency hiding):
//  - gate GEMV split by k-range dependency:
//      x-rows  (k 0..255):   depend only on x_{t+1} -> computed at tail of t
//                            (hides barrier B poll), ping-pong zbuf[2][256]
//      h-rows  (k 768..1023): depend only on h_{t-1} -> computed between
//                            barrier-A signal and poll (hides barrier A)
//      ctx-rows(k 256..767): post-merge; weights prefetched into 8 uint4
//                            registers before the A-poll (half the stream)
//  - P1 logits: conflict-free direct stores into lds_logit4[4][256]
//  - x_{t+1} global load hoisted to loop top
// R6:
//  - Wab (s-update weights, 128 B/thread) resident in registers for the whole
//    scan: s-update is pure LDS+VALU, no per-step L2 stream / load stall
//  - y-norm moved into the NEXT step's barrier-A window (cat[768..] still
//    holds h_{t-1} there; y_out is not consumed by the recurrence) and
//    distributed: every WG writes its own 64-wide slice -> no q==0 straggler
__global__ __launch_bounds__(1024) void scan_kernel(
    const float* __restrict__ x_seq, float* __restrict__ y_out,
    const unsigned short* __restrict__ enc, const unsigned short* __restrict__ speech,
    const unsigned short* __restrict__ KRP, const unsigned short* __restrict__ Wab,
    const float* __restrict__ Wa_b, const float* __restrict__ va,
    const float* __restrict__ gate_b,
    float* __restrict__ pctx_g, float* __restrict__ l_g, float* __restrict__ h_g,
    unsigned int* __restrict__ ctr){
  extern __shared__ __align__(16) unsigned short enc_l[];   // [256][264] = 132 KB
  __shared__ float2 sva[256];        // (s[u], va[u])
  __shared__ float cat[1024];        // [0,256)=x_t  [256,768)=ctx  [768,1024)=h_{t-1}
  __shared__ float c_lds[64];
  __shared__ float lds_logit4[1024]; // [4 u-quarters][256 te]
  __shared__ float p_lds[256];
  __shared__ float lds_pctx[512];
  __shared__ float zbuf[2][256];     // gate accumulators, ping-pong over t
  __shared__ float s_acc[256];
  __shared__ float red[32];
  __shared__ float nmi[2];

  const int tid = threadIdx.x;
  const int wg = blockIdx.x;
  const int b = wg >> 2, q = wg & 3;
  const int lane = tid & 63, wave = tid >> 6;
  unsigned int bar = 0;
  unsigned int* cptr = &ctr[b*16];

  // one-time: stage this WG's enc slice (256 te x 256 u bf16) into LDS
  {
    const uint4* ep4 = (const uint4*)(enc + ((size_t)b*TE + q*256)*UU);
    #pragma unroll
    for (int i = 0; i < 8; ++i){
      int idx = tid + 1024*i;                   // 8192 uint4
      int te_l = idx >> 5, ch = idx & 31;
      uint4 v = ep4[(size_t)te_l*32 + ch];
      *(uint4*)(enc_l + (size_t)te_l*264 + ch*8) = v;
    }
  }
  if (tid < 256){ sva[tid] = make_float2(Wa_b[tid], va[tid]); cat[768 + tid] = 0.f;
                  zbuf[0][tid] = 0.f; zbuf[1][tid] = 0.f; }
  if (tid < 64) c_lds[tid] = 0.f;
  if (tid >= 512 && tid < 768)
    cat[tid - 512] = x_seq[((size_t)b*TD + 0)*UU + (tid - 512)];

  // one-time: Wab weights resident in registers (128 B/thread = 8 uint4)
  uint4 wab[8];
  {
    const int c = tid & 31, kg = tid >> 5;
    const uint4* wp = (const uint4*)Wab + (size_t)(kg*8)*32 + c;
    #pragma unroll
    for (int i = 0; i < 8; ++i) wab[i] = wp[(size_t)i*32];
  }
  __syncthreads();
  // prologue: x-rows gate contribution for t=0
  gate_accum<8>(KRP, cat, zbuf[0], q, 0, tid, lane);

  for (int t = 0; t < TD; ++t){
    // ---- loop top: zero scratch, issue x_{t+1} load (held in register) ----
    if (tid < 512) lds_pctx[tid] = 0.f;
    if (tid < 256){ zbuf[(t+1)&1][tid] = 0.f; s_acc[tid] = 0.f; }
    float xnext = 0.f;
    if (t < TD-1 && tid >= 512 && tid < 768)
      xnext = x_seq[((size_t)b*TD + t + 1)*UU + (tid - 512)];
    __syncthreads();

    // ---- P1: attention logits from LDS enc (conflict-free partial stores) ----
    {
      const int g = wave & 3, r = wave >> 2;
      const int te_l = g*64 + lane;             // local te 0..255
      const unsigned short* ep = enc_l + (size_t)te_l*264 + r*64;
      float acc = 0.f;
      #pragma unroll
      for (int c = 0; c < 8; ++c){
        uint4 v = *(const uint4*)(ep + c*8);
        const int ub = r*64 + c*8;
        unsigned int wv[4] = {v.x, v.y, v.z, v.w};
        #pragma unroll
        for (int i = 0; i < 4; ++i){
          float2 s0 = sva[ub + 2*i];
          float2 s1 = sva[ub + 2*i + 1];
          acc += s0.y * tanh_fast(s0.x + bflo(wv[i]));
          acc += s1.y * tanh_fast(s1.x + bfhi(wv[i]));
        }
      }
      lds_logit4[r*256 + te_l] = acc;           // unique (r,te_l) per thread
    }
    __syncthreads();

    // ---- P2: p = exp(logit), wave partial sums ----
    if (tid < 256){
      float lg = lds_logit4[tid] + lds_logit4[256 + tid]
               + lds_logit4[512 + tid] + lds_logit4[768 + tid];
      float p = fexp2(lg * 1.442695041f);
      p_lds[tid] = p;
      float s = p;
      #pragma unroll
      for (int o = 32; o > 0; o >>= 1) s += __shfl_xor(s, o);
      if (lane == 0) red[wave] = s;
    }
    __syncthreads();

    // ---- P3: partial ctx = sum_te p[te]*speech[te][:]  (uint4 stream) ----
    {
      const int c = tid & 63, tg = tid >> 6;    // e-chunk (8 e), te-group (16 te)
      const uint4* sp4 = (const uint4*)speech + ((size_t)b*TE + q*256 + tg*16)*64 + c;
      float a0=0.f,a1=0.f,a2=0.f,a3=0.f,a4=0.f,a5=0.f,a6=0.f,a7=0.f;
      #pragma unroll 4
      for (int i = 0; i < 16; ++i){
        uint4 w = sp4[(size_t)i*64];
        float p = p_lds[tg*16 + i];
        a0 += p*bflo(w.x); a1 += p*bfhi(w.x);
        a2 += p*bflo(w.y); a3 += p*bfhi(w.y);
        a4 += p*bflo(w.z); a5 += p*bfhi(w.z);
        a6 += p*bflo(w.w); a7 += p*bfhi(w.w);
      }
      atomicAdd(&lds_pctx[c*8+0], a0); atomicAdd(&lds_pctx[c*8+1], a1);
      atomicAdd(&lds_pctx[c*8+2], a2); atomicAdd(&lds_pctx[c*8+3], a3);
      atomicAdd(&lds_pctx[c*8+4], a4); atomicAdd(&lds_pctx[c*8+5], a5);
      atomicAdd(&lds_pctx[c*8+6], a6); atomicAdd(&lds_pctx[c*8+7], a7);
    }
    __syncthreads();
    if (tid < 512) gstore(&pctx_g[((size_t)(b*4 + q))*512 + tid], lds_pctx[tid]);
    if (tid == 0)  gstore(&l_g[b*4 + q], red[0] + red[1] + red[2] + red[3]);
    drain_stores();
    __syncthreads();
    // ---- barrier A signal (poll deferred: window work hides it) ----
    bar += 4;
    if (tid == 0)
      __hip_atomic_fetch_add(cptr, 1u, __ATOMIC_RELAXED, __HIP_MEMORY_SCOPE_SYSTEM);

    // ---- A-window 1: gate h-rows (k 768..1023), needs only h_{t-1} ----
    gate_accum<8>(KRP, cat, zbuf[t&1], q, 768, tid, lane);

    // ---- A-window 2: prefetch first half of ctx-row weights ----
    uint4 pf[8];
    {
      const int c = tid & 31, kg = tid >> 5;
      const uint4* kp = (const uint4*)KRP + ((size_t)q*1024 + 256 + kg*16)*32 + c;
      #pragma unroll
      for (int i = 0; i < 8; ++i) pf[i] = kp[(size_t)i*32];
    }

    // ---- A-window 3: y_{t-1} = whatever_norm(h_{t-1}) (off critical path;
    //      all WGs reduce redundantly, each writes its own 64-wide slice) ----
    if (t > 0){
      if (tid < 256){
        float hv = cat[768 + tid];
        float s1 = hv, s2 = hv*hv;
        #pragma unroll
        for (int o = 32; o > 0; o >>= 1){ s1 += __shfl_xor(s1, o); s2 += __shfl_xor(s2, o); }
        if (lane == 0){ red[wave*2] = s1; red[wave*2 + 1] = s2; }
      }
      __syncthreads();
      if (tid == 0){
        float m  = (red[0] + red[2] + red[4] + red[6]) * (1.f/256.f);
        float ms = (red[1] + red[3] + red[5] + red[7]) * (1.f/256.f);
        nmi[0] = m;
        nmi[1] = rsqrtf(ms - m*m + 1e-4f);
      }
      __syncthreads();
      if (tid < 64)
        y_out[((size_t)b*TD + (t-1))*UU + q*64 + tid] =
            (cat[768 + q*64 + tid] - nmi[0]) * nmi[1];
    }

    // ---- barrier A poll ----
    if (tid == 0){
      while (__hip_atomic_load(cptr, __ATOMIC_RELAXED, __HIP_MEMORY_SCOPE_SYSTEM) < bar)
        __builtin_amdgcn_s_sleep(2);
    }
    __syncthreads();

    // ---- merge ctx ----
    if (tid < 512){
      float l0 = gload(&l_g[b*4+0]), l1 = gload(&l_g[b*4+1]);
      float l2 = gload(&l_g[b*4+2]), l3 = gload(&l_g[b*4+3]);
      float linv = frcp_(l0 + l1 + l2 + l3);
      float s0 = gload(&pctx_g[((size_t)(b*4+0))*512 + tid])
               + gload(&pctx_g[((size_t)(b*4+1))*512 + tid])
               + gload(&pctx_g[((size_t)(b*4+2))*512 + tid])
               + gload(&pctx_g[((size_t)(b*4+3))*512 + tid]);
      cat[256 + tid] = s0 * linv;
    }
    __syncthreads();

    // ---- gate ctx-rows (k 256..767): half from prefetch regs, half loaded ----
    {
      const int c = tid & 31, kg = tid >> 5;
      const uint4* kp = (const uint4*)KRP + ((size_t)q*1024 + 256 + kg*16)*32 + c;
      float a0=0.f,a1=0.f,a2=0.f,a3=0.f,a4=0.f,a5=0.f,a6=0.f,a7=0.f;
      #pragma unroll
      for (int i = 0; i < 8; ++i){
        uint4 w = pf[i];
        float ck = cat[256 + kg*16 + i];
        a0 += ck*bflo(w.x); a1 += ck*bfhi(w.x);
        a2 += ck*bflo(w.y); a3 += ck*bfhi(w.y);
        a4 += ck*bflo(w.z); a5 += ck*bfhi(w.z);
        a6 += ck*bflo(w.w); a7 += ck*bfhi(w.w);
      }
      #pragma unroll 4
      for (int i = 8; i < 16; ++i){
        uint4 w = kp[(size_t)i*32];
        float ck = cat[256 + kg*16 + i];
        a0 += ck*bflo(w.x); a1 += ck*bfhi(w.x);
        a2 += ck*bflo(w.y); a3 += ck*bfhi(w.y);
        a4 += ck*bflo(w.z); a5 += ck*bfhi(w.z);
        a6 += ck*bflo(w.w); a7 += ck*bfhi(w.w);
      }
      a0 += __shfl_xor(a0, 32); a1 += __shfl_xor(a1, 32);
      a2 += __shfl_xor(a2, 32); a3 += __shfl_xor(a3, 32);
      a4 += __shfl_xor(a4, 32); a5 += __shfl_xor(a5, 32);
      a6 += __shfl_xor(a6, 32); a7 += __shfl_xor(a7, 32);
      float* zb = zbuf[t&1];
      if (lane < 32){
        atomicAdd(&zb[c*8+0], a0); atomicAdd(&zb[c*8+1], a1);
        atomicAdd(&zb[c*8+2], a2); atomicAdd(&zb[c*8+3], a3);
        atomicAdd(&zb[c*8+4], a4); atomicAdd(&zb[c*8+5], a5);
        atomicAdd(&zb[c*8+6], a6); atomicAdd(&zb[c*8+7], a7);
      }
    }
    __syncthreads();

    // ---- LSTM pointwise (keras i,f,g,o), export h slice ----
    if (tid < 64){
      const int jj = q*64 + tid;
      const float* zb = zbuf[t&1];
      float zi = zb[tid]       + gate_b[jj];
      float zf = zb[64 + tid]  + gate_b[256 + jj];
      float zg = zb[128 + tid] + gate_b[512 + jj];
      float zo = zb[192 + tid] + gate_b[768 + jj];
      float cn = sigmoid_fast(zf) * c_lds[tid] + sigmoid_fast(zi) * tanh_fast(zg);
      c_lds[tid] = cn;
      gstore(&h_g[(size_t)b*UU + jj], sigmoid_fast(zo) * tanh_fast(cn));
    }
    // park x_{t+1} (loaded at loop top) into cat[0..256)
    if (t < TD-1 && tid >= 512 && tid < 768) cat[tid - 512] = xnext;
    drain_stores();
    __syncthreads();
    // ---- barrier B signal (poll deferred: x-rows of t+1 hide it) ----
    bar += 4;
    if (tid == 0)
      __hip_atomic_fetch_add(cptr, 1u, __ATOMIC_RELAXED, __HIP_MEMORY_SCOPE_SYSTEM);

    // ---- B-window: gate x-rows for t+1 (k 0..255), needs only x_{t+1} ----
    if (t < TD-1)
      gate_accum<8>(KRP, cat, zbuf[(t+1)&1], q, 0, tid, lane);

    // ---- barrier B poll ----
    if (tid == 0){
      while (__hip_atomic_load(cptr, __ATOMIC_RELAXED, __HIP_MEMORY_SCOPE_SYSTEM) < bar)
        __builtin_amdgcn_s_sleep(2);
    }
    __syncthreads();

    if (tid < 256) cat[768 + tid] = gload(&h_g[(size_t)b*UU + tid]);
    __syncthreads();

    // ---- s_{t+1} = h_t @ Wa + Wa_b (register-resident Wab, pure LDS+VALU) ----
    if (t < TD - 1){
      {
        const int c = tid & 31, kg = tid >> 5;  // u-chunk (8 u), k-group (8 k)
        float a0=0.f,a1=0.f,a2=0.f,a3=0.f,a4=0.f,a5=0.f,a6=0.f,a7=0.f;
        #pragma unroll
        for (int i = 0; i < 8; ++i){
          uint4 w = wab[i];
          float hk = cat[768 + kg*8 + i];
          a0 += hk*bflo(w.x); a1 += hk*bfhi(w.x);
          a2 += hk*bflo(w.y); a3 += hk*bfhi(w.y);
          a4 += hk*bflo(w.z); a5 += hk*bfhi(w.z);
          a6 += hk*bflo(w.w); a7 += hk*bfhi(w.w);
        }
        a0 += __shfl_xor(a0, 32); a1 += __shfl_xor(a1, 32);
        a2 += __shfl_xor(a2, 32); a3 += __shfl_xor(a3, 32);
        a4 += __shfl_xor(a4, 32); a5 += __shfl_xor(a5, 32);
        a6 += __shfl_xor(a6, 32); a7 += __shfl_xor(a7, 32);
        if (lane < 32){
          atomicAdd(&s_acc[c*8+0], a0); atomicAdd(&s_acc[c*8+1], a1);
          atomicAdd(&s_acc[c*8+2], a2); atomicAdd(&s_acc[c*8+3], a3);
          atomicAdd(&s_acc[c*8+4], a4); atomicAdd(&s_acc[c*8+5], a5);
          atomicAdd(&s_acc[c*8+6], a6); atomicAdd(&s_acc[c*8+7], a7);
        }
      }
      __syncthreads();
      if (tid < 256) sva[tid].x = Wa_b[tid] + s_acc[tid];
    }
    __syncthreads();
  }

  // ---- epilogue: y_{TD-1} = whatever_norm(h_{TD-1}) ----
  {
    if (tid < 256){
      float hv = cat[768 + tid];
      float s1 = hv, s2 = hv*hv;
      #pragma unroll
      for (int o = 32; o > 0; o >>= 1){ s1 += __shfl_xor(s1, o); s2 += __shfl_xor(s2, o); }
      if (lane == 0){ red[wave*2] = s1; red[wave*2 + 1] = s2; }
    }
    __syncthreads();
    if (tid == 0){
      float m  = (red[0] + red[2] + red[4] + red[6]) * (1.f/256.f);
      float ms = (red[1] + red[3] + red[5] + red[7]) * (1.f/256.f);
      nmi[0] = m;
      nmi[1] = rsqrtf(ms - m*m + 1e-4f);
    }
    __syncthreads();
    if (tid < 64)
      y_out[((size_t)b*TD + (TD-1))*UU + q*64 + tid] =
          (cat[768 + q*64 + tid] - nmi[0]) * nmi[1];
  }
}

// ---------- head: norm(norm(y2@m1+b)@m2+b)@dW+db -> softmax ----------
__global__ __launch_bounds__(256) void head_kernel(const float* __restrict__ y2,
    const float* __restrict__ m1W, const float* __restrict__ m1b,
    const float* __restrict__ m2W, const float* __restrict__ m2b,
    const float* __restrict__ dW, const float* __restrict__ db,
    float* __restrict__ out){
  __shared__ __align__(16) float aT[256*20];
  __shared__ float t_lds[16*256];
  __shared__ float zl[16*64];
  __shared__ float mi[32];
  const int row0 = blockIdx.x * 16;
  const int tid = threadIdx.x;
  for (int it = 0; it < 16; ++it){
    int idx = tid + 256*it;
    int r = idx >> 8, k = idx & 255;
    aT[k*20 + r] = y2[(size_t)(row0 + r)*UU + k];
  }
  __syncthreads();

  #pragma unroll 1
  for (int pass = 0; pass < 2; ++pass){
    const float* Wp = pass ? m2W : m1W;
    const float* bp = pass ? m2b : m1b;
    const int j = tid;
    float bj = bp[j];
    float acc[16];
    #pragma unroll
    for (int r = 0; r < 16; ++r) acc[r] = bj;
    for (int k = 0; k < 256; ++k){
      float w = Wp[(size_t)k*UU + j];
      const float4* a4 = (const float4*)(aT + k*20);
      float4 q0 = a4[0], q1 = a4[1], q2 = a4[2], q3 = a4[3];
      acc[0]+=q0.x*w;  acc[1]+=q0.y*w;  acc[2]+=q0.z*w;  acc[3]+=q0.w*w;
      acc[4]+=q1.x*w;  acc[5]+=q1.y*w;  acc[6]+=q1.z*w;  acc[7]+=q1.w*w;
      acc[8]+=q2.x*w;  acc[9]+=q2.y*w;  acc[10]+=q2.z*w; acc[11]+=q2.w*w;
      acc[12]+=q3.x*w; acc[13]+=q3.y*w; acc[14]+=q3.z*w; acc[15]+=q3.w*w;
    }
    #pragma unroll
    for (int r = 0; r < 16; ++r) t_lds[r*256 + j] = acc[r];
    __syncthreads();
    {
      int r = tid >> 4, sg = tid & 15;
      float s1 = 0.f, s2 = 0.f;
      for (int c = 0; c < 16; ++c){
        float v = t_lds[r*256 + sg*16 + c];
        s1 += v; s2 += v*v;
      }
      for (int o = 1; o < 16; o <<= 1){ s1 += __shfl_xor(s1, o); s2 += __shfl_xor(s2, o); }
      if (sg == 0){
        float m = s1 * (1.f/256.f);
        float vv = s2 * (1.f/256.f) - m*m;
        mi[r*2] = m; mi[r*2+1] = rsqrtf(vv + 1e-4f);
      }
    }
    __syncthreads();
    {
      const int j2 = tid;
      #pragma unroll
      for (int r = 0; r < 16; ++r)
        aT[j2*20 + r] = (t_lds[r*256 + j2] - mi[r*2]) * mi[r*2+1];
    }
    __syncthreads();
  }

  for (int i = tid; i < 1024; i += 256) zl[i] = 0.f;
  __syncthreads();
  {
    const int j = tid & 63, kq = tid >> 6;
    float acc[16];
    #pragma unroll
    for (int r = 0; r < 16; ++r) acc[r] = 0.f;
    for (int k = 0; k < 64; ++k){
      float w = dW[(size_t)(kq*64 + k)*64 + j];
      const float4* a4 = (const float4*)(aT + (kq*64 + k)*20);
      float4 q0 = a4[0], q1 = a4[1], q2 = a4[2], q3 = a4[3];
      acc[0]+=q0.x*w;  acc[1]+=q0.y*w;  acc[2]+=q0.z*w;  acc[3]+=q0.w*w;
      acc[4]+=q1.x*w;  acc[5]+=q1.y*w;  acc[6]+=q1.z*w;  acc[7]+=q1.w*w;
      acc[8]+=q2.x*w;  acc[9]+=q2.y*w;  acc[10]+=q2.z*w; acc[11]+=q2.w*w;
      acc[12]+=q3.x*w; acc[13]+=q3.y*w; acc[14]+=q3.z*w; acc[15]+=q3.w*w;
    }
    #pragma unroll
    for (int r = 0; r < 16; ++r) atomicAdd(&zl[r*64 + j], acc[r]);
  }
  __syncthreads();
  if (tid < 16){
    const int r = tid;
    float mx = -1e30f;
    for (int j = 0; j < 64; ++j){ float v = zl[r*64 + j] + db[j]; zl[r*64 + j] = v; mx = fmaxf(mx, v); }
    float s = 0.f;
    for (int j = 0; j < 64; ++j){ float e = fexp2((zl[r*64 + j] - mx) * 1.442695041f); zl[r*64 + j] = e; s += e; }
    mi[r] = frcp_(s);
  }
  __syncthreads();
  for (int it = 0; it < 4; ++it){
    int idx = tid + 256*it;
    int r = idx >> 6, j = idx & 63;
    out[(size_t)(row0 + r)*64 + j] = zl[r*64 + j] * mi[r];
  }
}

// ---------- workspace layout (bytes) ----------
#define OFF_SPEECH 0u
#define OFF_ENC    67108864u
#define OFF_KR     100663296u
#define OFF_WA     102760448u
#define OFF_X1     102891520u
#define OFF_Y1     136445952u
#define OFF_PCTX   170000384u
#define OFF_L      170524672u
#define OFF_H      170528768u
#define OFF_CTR    170594304u

#define DYN_LDS    135168    // 256 rows x 264 ushorts

extern "C" void kernel_launch(void* const* d_in, const int* in_sizes, int n_in,
                              void* d_out, int out_size, void* d_ws, size_t ws_size,
                              hipStream_t stream){
  const float* trans  = (const float*)d_in[0];
  const float* speech = (const float*)d_in[1];
  const float* emb_W  = (const float*)d_in[2];
  const float* emb_b  = (const float*)d_in[3];
  const float* Ua_W[2]  = {(const float*)d_in[4],  (const float*)d_in[13]};
  const float* Ua_b[2]  = {(const float*)d_in[5],  (const float*)d_in[14]};
  const float* Wa_W[2]  = {(const float*)d_in[6],  (const float*)d_in[15]};
  const float* Wa_bv[2] = {(const float*)d_in[7],  (const float*)d_in[16]};
  const float* va_W[2]  = {(const float*)d_in[8],  (const float*)d_in[17]};
  // d_in[9]/d_in[18] = va_b: constant logit shift, softmax-invariant, dropped exactly.
  const float* Kw[2]    = {(const float*)d_in[10], (const float*)d_in[19]};
  const float* Rw[2]    = {(const float*)d_in[11], (const float*)d_in[20]};
  const float* bw[2]    = {(const float*)d_in[12], (const float*)d_in[21]};
  const float* m1W = (const float*)d_in[22];
  const float* m1b = (const float*)d_in[23];
  const float* m2W = (const float*)d_in[24];
  const float* m2b = (const float*)d_in[25];
  const float* dW  = (const float*)d_in[26];
  const float* db  = (const float*)d_in[27];

  char* ws = (char*)d_ws;
  unsigned short* speech_bf = (unsigned short*)(ws + OFF_SPEECH);
  unsigned short* enc  = (unsigned short*)(ws + OFF_ENC);
  unsigned short* KRP  = (unsigned short*)(ws + OFF_KR);
  unsigned short* Wab  = (unsigned short*)(ws + OFF_WA);
  float* x1   = (float*)(ws + OFF_X1);
  float* y1   = (float*)(ws + OFF_Y1);
  float* pctx = (float*)(ws + OFF_PCTX);
  float* lg   = (float*)(ws + OFF_L);
  float* hg   = (float*)(ws + OFF_H);
  unsigned int* ctr = (unsigned int*)(ws + OFF_CTR);
  float* y2 = x1;   // x1 dead after scan1 consumes it

  hipFuncSetAttribute((const void*)scan_kernel,
                      hipFuncAttributeMaxDynamicSharedMemorySize, DYN_LDS);

  hipMemsetAsync(ctr, 0, 4096, stream);
  pack_bf16v<<<4096, 256, 0, stream>>>(speech, speech_bf, B*TE*EE/4);
  emb_gemm<<<2048, 256, 0, stream>>>(trans, emb_W, emb_b, x1);

  for (int L = 0; L < 2; ++L){
    enc_gemm<<<4096, 256, 0, stream>>>(speech, Ua_W[L], Ua_b[L], enc);
    pack_KRP<<<4096, 256, 0, stream>>>(Kw[L], Rw[L], KRP);
    pack_bf16v<<<64, 256, 0, stream>>>(Wa_W[L], Wab, UU*UU/4);
    if (L == 1) hipMemsetAsync(ctr, 0, 4096, stream);
    scan_kernel<<<256, 1024, DYN_LDS, stream>>>(L == 0 ? x1 : y1, L == 0 ? y1 : y2,
        enc, speech_bf, KRP, Wab, Wa_bv[L], va_W[L], bw[L], pctx, lg, hg, ctr);
  }

  head_kernel<<<2048, 256, 0, stream>>>(y2, m1W, m1b, m2W, m2b, dW, db, (float*)d_out);
  (void)in_sizes; (void)n_in; (void)out_size; (void)ws_size;
}

// Round 3
// 79404.266 us; speedup vs baseline: 1.0039x; 1.0039x over previous
//
#include <hip/hip_runtime.h>
#include <hip/hip_bf16.h>
#include <stdint.h>

#define B  64
#define TD 512
#define TE 1024
#define EE 512
#define UU 256

// ---------- numeric helpers ----------
__device__ __forceinline__ float fexp2(float x){ return __builtin_amdgcn_exp2f(x); }
__device__ __forceinline__ float frcp_(float x){ return __builtin_amdgcn_rcpf(x); }
__device__ __forceinline__ float tanh_fast(float x){
  float e = fexp2(x * 2.885390082f);
  return 1.f - 2.f * frcp_(e + 1.f);
}
__device__ __forceinline__ float sigmoid_fast(float x){
  return frcp_(1.f + fexp2(-1.442695041f * x));
}
__device__ __forceinline__ unsigned short f2bf(float f){
  unsigned int u = __float_as_uint(f);
  u = (u + 0x7fffu + ((u >> 16) & 1u)) >> 16;   // RNE
  return (unsigned short)u;
}
__device__ __forceinline__ float bflo(unsigned int w){ return __uint_as_float(w << 16); }
__device__ __forceinline__ float bfhi(unsigned int w){ return __uint_as_float(w & 0xffff0000u); }

// Cross-XCD comm WITHOUT cache flushes: relaxed system-scope ops lower to
// global_load/store/atomic with sc0 sc1 (bypass L1/L2, coherent at L3) and
// never emit buffer_inv/buffer_wbl2 -> L2 stays hot for speech/KR.
__device__ __forceinline__ void gstore(float* p, float v){
  __hip_atomic_store(p, v, __ATOMIC_RELAXED, __HIP_MEMORY_SCOPE_SYSTEM);
}
__device__ __forceinline__ float gload(const float* p){
  return __hip_atomic_load(p, __ATOMIC_RELAXED, __HIP_MEMORY_SCOPE_SYSTEM);
}
__device__ __forceinline__ void drain_stores(){
  __atomic_signal_fence(__ATOMIC_SEQ_CST);
  __builtin_amdgcn_s_waitcnt(0);
  __atomic_signal_fence(__ATOMIC_SEQ_CST);
}

// Gate partial GEMV over k-range [k0, k0+32*NITER) of this WG's KRP slice,
// accumulating into LDS zb[256] (jj = (tid&31)*8 + i). Used for the x-rows
// (k0=0, runs one timestep EARLY to hide barrier B) and h-rows (k0=768,
// runs between barrier-A signal and poll to hide barrier A).
template<int NITER>
__device__ __forceinline__ void gate_accum(const unsigned short* __restrict__ KRP,
    const float* catp, float* zb, int q, int k0, int tid, int lane){
  const int c = tid & 31, kg = tid >> 5;
  const uint4* kp = (const uint4*)KRP + ((size_t)q*1024 + k0 + kg*NITER)*32 + c;
  float a0=0.f,a1=0.f,a2=0.f,a3=0.f,a4=0.f,a5=0.f,a6=0.f,a7=0.f;
  #pragma unroll 4
  for (int i = 0; i < NITER; ++i){
    uint4 w = kp[(size_t)i*32];
    float ck = catp[k0 + kg*NITER + i];
    a0 += ck*bflo(w.x); a1 += ck*bfhi(w.x);
    a2 += ck*bflo(w.y); a3 += ck*bfhi(w.y);
    a4 += ck*bflo(w.z); a5 += ck*bfhi(w.z);
    a6 += ck*bflo(w.w); a7 += ck*bfhi(w.w);
  }
  a0 += __shfl_xor(a0, 32); a1 += __shfl_xor(a1, 32);
  a2 += __shfl_xor(a2, 32); a3 += __shfl_xor(a3, 32);
  a4 += __shfl_xor(a4, 32); a5 += __shfl_xor(a5, 32);
  a6 += __shfl_xor(a6, 32); a7 += __shfl_xor(a7, 32);
  if (lane < 32){
    atomicAdd(&zb[c*8+0], a0); atomicAdd(&zb[c*8+1], a1);
    atomicAdd(&zb[c*8+2], a2); atomicAdd(&zb[c*8+3], a3);
    atomicAdd(&zb[c*8+4], a4); atomicAdd(&zb[c*8+5], a5);
    atomicAdd(&zb[c*8+6], a6); atomicAdd(&zb[c*8+7], a7);
  }
}

// ---------- pack kernels ----------
__global__ void pack_bf16v(const float* __restrict__ in, unsigned short* __restrict__ out, int n4){
  int i = blockIdx.x * blockDim.x + threadIdx.x;
  int stride = gridDim.x * blockDim.x;
  for (; i < n4; i += stride){
    float4 v = ((const float4*)in)[i];
    ushort4 o;
    o.x = f2bf(v.x); o.y = f2bf(v.y); o.z = f2bf(v.z); o.w = f2bf(v.w);
    ((ushort4*)out)[i] = o;
  }
}

// KRP[q][k][jj]: per-WG-contiguous gate weights. jj in [0,256) maps to
// logical column J = (jj>>6)*256 + q*64 + (jj&63); rows 0..767 = K, 768..1023 = R.
// Total elements = 4*1024*256 = 1,048,576 -> grid MUST be 4096 x 256 (R4 bug: 8192
// overran the 2 MB buffer and trashed Wab/x1).
__global__ void pack_KRP(const float* __restrict__ K, const float* __restrict__ R,
                         unsigned short* __restrict__ KRP){
  int idx = blockIdx.x * 256 + threadIdx.x;    // 4096 blocks -> 1M exactly
  int q  = idx >> 18;
  int k  = (idx >> 8) & 1023;
  int jj = idx & 255;
  int J  = (jj >> 6)*256 + q*64 + (jj & 63);
  float v = (k < 768) ? K[(size_t)k*1024 + J] : R[(size_t)(k - 768)*1024 + J];
  KRP[idx] = f2bf(v);
}

// ---------- secrets = trans @ emb_W + emb_b : [32768,64]@[64,256] ----------
__global__ __launch_bounds__(256) void emb_gemm(const float* __restrict__ trans,
    const float* __restrict__ W, const float* __restrict__ bias, float* __restrict__ out){
  __shared__ __align__(16) float aT[64*20];
  const int row0 = blockIdx.x * 16;
  const int tid = threadIdx.x;
  {
    int r = tid >> 6, k = tid & 63;
    for (int rr = r; rr < 16; rr += 4)
      aT[k*20 + rr] = trans[(size_t)(row0 + rr)*64 + k];
  }
  __syncthreads();
  const int j = tid;
  float bj = bias[j];
  float acc[16];
  #pragma unroll
  for (int r = 0; r < 16; ++r) acc[r] = bj;
  for (int k = 0; k < 64; ++k){
    float w = W[(size_t)k*UU + j];
    const float4* a4 = (const float4*)(aT + k*20);
    float4 q0 = a4[0], q1 = a4[1], q2 = a4[2], q3 = a4[3];
    acc[0]+=q0.x*w;  acc[1]+=q0.y*w;  acc[2]+=q0.z*w;  acc[3]+=q0.w*w;
    acc[4]+=q1.x*w;  acc[5]+=q1.y*w;  acc[6]+=q1.z*w;  acc[7]+=q1.w*w;
    acc[8]+=q2.x*w;  acc[9]+=q2.y*w;  acc[10]+=q2.z*w; acc[11]+=q2.w*w;
    acc[12]+=q3.x*w; acc[13]+=q3.y*w; acc[14]+=q3.z*w; acc[15]+=q3.w*w;
  }
  #pragma unroll
  for (int r = 0; r < 16; ++r)
    out[(size_t)(row0 + r)*UU + j] = acc[r];
}

// ---------- enc = speech @ Ua + Ua_b, stored bf16 [B][TE][U] ----------
__global__ __launch_bounds__(256) void enc_gemm(const float* __restrict__ speech,
    const float* __restrict__ Ua, const float* __restrict__ Uab,
    unsigned short* __restrict__ enc){
  __shared__ __align__(16) float aT[512*20];
  const int wg = blockIdx.x;
  const int b = wg >> 6, tb = (wg & 63) * 16;
  const int tid = threadIdx.x;
  const float* sp = speech + ((size_t)b*TE + tb)*EE;
  for (int it = 0; it < 32; ++it){
    int idx = tid + 256*it;
    int te = idx >> 9, e = idx & 511;
    aT[e*20 + te] = sp[(size_t)te*EE + e];
  }
  __syncthreads();
  const int j = tid;
  float bj = Uab[j];
  float acc[16];
  #pragma unroll
  for (int r = 0; r < 16; ++r) acc[r] = bj;
  const float* up = Ua + j;
  for (int e = 0; e < 512; ++e){
    float w = up[(size_t)e*UU];
    const float4* a4 = (const float4*)(aT + e*20);
    float4 q0 = a4[0], q1 = a4[1], q2 = a4[2], q3 = a4[3];
    acc[0]+=q0.x*w;  acc[1]+=q0.y*w;  acc[2]+=q0.z*w;  acc[3]+=q0.w*w;
    acc[4]+=q1.x*w;  acc[5]+=q1.y*w;  acc[6]+=q1.z*w;  acc[7]+=q1.w*w;
    acc[8]+=q2.x*w;  acc[9]+=q2.y*w;  acc[10]+=q2.z*w; acc[11]+=q2.w*w;
    acc[12]+=q3.x*w; acc[13]+=q3.y*w; acc[14]+=q3.z*w; acc[15]+=q3.w*w;
  }
  unsigned short* op = enc + ((size_t)b*TE + tb)*UU + j;
  #pragma unroll
  for (int r = 0; r < 16; ++r) op[(size_t)r*UU] = f2bf(acc[r]);
}

// ---------- persistent attention-LSTM scan ----------
// grid 256 = 64 batches x 4 WGs; 1024 threads. enc slice persisted in dynamic
// LDS (132 KB, stride 264 ushorts). All big streams are uint4 rolled loops.
// 4-WG barriers: relaxed system-scope counter (no cache flushes).
//
// R5: gate GEMV split by dependency (x-rows early / h-rows in A-window /
//     ctx-rows post-merge with reg prefetch); conflict-free P1 stores.
// R6: Wab register-resident; y-norm in A-window, distributed across WGs.
// R7: __launch_bounds__(1024, 4). LDS (148 KB) caps us at 1 WG/CU = 4
//     waves/SIMD, but the compiler's default heuristic capped VGPRs at 64
//     (targeting a useless 8 waves/SIMD) -> R6's wab[8] was SPILLED to
//     scratch and reloaded from VRAM every step (FETCH +17.3 GB == exactly
//     128 B/thread/step; floor 31.7 -> 38.7 ms). The explicit bound lifts
//     the budget to 128 VGPRs so wab/pf are genuinely resident.
__global__ __launch_bounds__(1024, 4) void scan_kernel(
    const float* __restrict__ x_seq, float* __restrict__ y_out,
    const unsigned short* __restrict__ enc, const unsigned short* __restrict__ speech,
    const unsigned short* __restrict__ KRP, const unsigned short* __restrict__ Wab,
    const float* __restrict__ Wa_b, const float* __restrict__ va,
    const float* __restrict__ gate_b,
    float* __restrict__ pctx_g, float* __restrict__ l_g, float* __restrict__ h_g,
    unsigned int* __restrict__ ctr){
  extern __shared__ __align__(16) unsigned short enc_l[];   // [256][264] = 132 KB
  __shared__ float2 sva[256];        // (s[u], va[u])
  __shared__ float cat[1024];        // [0,256)=x_t  [256,768)=ctx  [768,1024)=h_{t-1}
  __shared__ float c_lds[64];
  __shared__ float lds_logit4[1024]; // [4 u-quarters][256 te]
  __shared__ float p_lds[256];
  __shared__ float lds_pctx[512];
  __shared__ float zbuf[2][256];     // gate accumulators, ping-pong over t
  __shared__ float s_acc[256];
  __shared__ float red[32];
  __shared__ float nmi[2];

  const int tid = threadIdx.x;
  const int wg = blockIdx.x;
  const int b = wg >> 2, q = wg & 3;
  const int lane = tid & 63, wave = tid >> 6;
  unsigned int bar = 0;
  unsigned int* cptr = &ctr[b*16];

  // one-time: stage this WG's enc slice (256 te x 256 u bf16) into LDS
  {
    const uint4* ep4 = (const uint4*)(enc + ((size_t)b*TE + q*256)*UU);
    #pragma unroll
    for (int i = 0; i < 8; ++i){
      int idx = tid + 1024*i;                   // 8192 uint4
      int te_l = idx >> 5, ch = idx & 31;
      uint4 v = ep4[(size_t)te_l*32 + ch];
      *(uint4*)(enc_l + (size_t)te_l*264 + ch*8) = v;
    }
  }
  if (tid < 256){ sva[tid] = make_float2(Wa_b[tid], va[tid]); cat[768 + tid] = 0.f;
                  zbuf[0][tid] = 0.f; zbuf[1][tid] = 0.f; }
  if (tid < 64) c_lds[tid] = 0.f;
  if (tid >= 512 && tid < 768)
    cat[tid - 512] = x_seq[((size_t)b*TD + 0)*UU + (tid - 512)];

  // one-time: Wab weights resident in registers (128 B/thread = 8 uint4)
  uint4 wab[8];
  {
    const int c = tid & 31, kg = tid >> 5;
    const uint4* wp = (const uint4*)Wab + (size_t)(kg*8)*32 + c;
    #pragma unroll
    for (int i = 0; i < 8; ++i) wab[i] = wp[(size_t)i*32];
  }
  __syncthreads();
  // prologue: x-rows gate contribution for t=0
  gate_accum<8>(KRP, cat, zbuf[0], q, 0, tid, lane);

  for (int t = 0; t < TD; ++t){
    // ---- loop top: zero scratch, issue x_{t+1} load (held in register) ----
    if (tid < 512) lds_pctx[tid] = 0.f;
    if (tid < 256){ zbuf[(t+1)&1][tid] = 0.f; s_acc[tid] = 0.f; }
    float xnext = 0.f;
    if (t < TD-1 && tid >= 512 && tid < 768)
      xnext = x_seq[((size_t)b*TD + t + 1)*UU + (tid - 512)];
    __syncthreads();

    // ---- P1: attention logits from LDS enc (conflict-free partial stores) ----
    {
      const int g = wave & 3, r = wave >> 2;
      const int te_l = g*64 + lane;             // local te 0..255
      const unsigned short* ep = enc_l + (size_t)te_l*264 + r*64;
      float acc = 0.f;
      #pragma unroll
      for (int c = 0; c < 8; ++c){
        uint4 v = *(const uint4*)(ep + c*8);
        const int ub = r*64 + c*8;
        unsigned int wv[4] = {v.x, v.y, v.z, v.w};
        #pragma unroll
        for (int i = 0; i < 4; ++i){
          float2 s0 = sva[ub + 2*i];
          float2 s1 = sva[ub + 2*i + 1];
          acc += s0.y * tanh_fast(s0.x + bflo(wv[i]));
          acc += s1.y * tanh_fast(s1.x + bfhi(wv[i]));
        }
      }
      lds_logit4[r*256 + te_l] = acc;           // unique (r,te_l) per thread
    }
    __syncthreads();

    // ---- P2: p = exp(logit), wave partial sums ----
    if (tid < 256){
      float lg = lds_logit4[tid] + lds_logit4[256 + tid]
               + lds_logit4[512 + tid] + lds_logit4[768 + tid];
      float p = fexp2(lg * 1.442695041f);
      p_lds[tid] = p;
      float s = p;
      #pragma unroll
      for (int o = 32; o > 0; o >>= 1) s += __shfl_xor(s, o);
      if (lane == 0) red[wave] = s;
    }
    __syncthreads();

    // ---- P3: partial ctx = sum_te p[te]*speech[te][:]  (uint4 stream) ----
    {
      const int c = tid & 63, tg = tid >> 6;    // e-chunk (8 e), te-group (16 te)
      const uint4* sp4 = (const uint4*)speech + ((size_t)b*TE + q*256 + tg*16)*64 + c;
      float a0=0.f,a1=0.f,a2=0.f,a3=0.f,a4=0.f,a5=0.f,a6=0.f,a7=0.f;
      #pragma unroll 4
      for (int i = 0; i < 16; ++i){
        uint4 w = sp4[(size_t)i*64];
        float p = p_lds[tg*16 + i];
        a0 += p*bflo(w.x); a1 += p*bfhi(w.x);
        a2 += p*bflo(w.y); a3 += p*bfhi(w.y);
        a4 += p*bflo(w.z); a5 += p*bfhi(w.z);
        a6 += p*bflo(w.w); a7 += p*bfhi(w.w);
      }
      atomicAdd(&lds_pctx[c*8+0], a0); atomicAdd(&lds_pctx[c*8+1], a1);
      atomicAdd(&lds_pctx[c*8+2], a2); atomicAdd(&lds_pctx[c*8+3], a3);
      atomicAdd(&lds_pctx[c*8+4], a4); atomicAdd(&lds_pctx[c*8+5], a5);
      atomicAdd(&lds_pctx[c*8+6], a6); atomicAdd(&lds_pctx[c*8+7], a7);
    }
    __syncthreads();
    if (tid < 512) gstore(&pctx_g[((size_t)(b*4 + q))*512 + tid], lds_pctx[tid]);
    if (tid == 0)  gstore(&l_g[b*4 + q], red[0] + red[1] + red[2] + red[3]);
    drain_stores();
    __syncthreads();
    // ---- barrier A signal (poll deferred: window work hides it) ----
    bar += 4;
    if (tid == 0)
      __hip_atomic_fetch_add(cptr, 1u, __ATOMIC_RELAXED, __HIP_MEMORY_SCOPE_SYSTEM);

    // ---- A-window 1: gate h-rows (k 768..1023), needs only h_{t-1} ----
    gate_accum<8>(KRP, cat, zbuf[t&1], q, 768, tid, lane);

    // ---- A-window 2: prefetch first half of ctx-row weights ----
    uint4 pf[8];
    {
      const int c = tid & 31, kg = tid >> 5;
      const uint4* kp = (const uint4*)KRP + ((size_t)q*1024 + 256 + kg*16)*32 + c;
      #pragma unroll
      for (int i = 0; i < 8; ++i) pf[i] = kp[(size_t)i*32];
    }

    // ---- A-window 3: y_{t-1} = whatever_norm(h_{t-1}) (off critical path;
    //      all WGs reduce redundantly, each writes its own 64-wide slice) ----
    if (t > 0){
      if (tid < 256){
        float hv = cat[768 + tid];
        float s1 = hv, s2 = hv*hv;
        #pragma unroll
        for (int o = 32; o > 0; o >>= 1){ s1 += __shfl_xor(s1, o); s2 += __shfl_xor(s2, o); }
        if (lane == 0){ red[wave*2] = s1; red[wave*2 + 1] = s2; }
      }
      __syncthreads();
      if (tid == 0){
        float m  = (red[0] + red[2] + red[4] + red[6]) * (1.f/256.f);
        float ms = (red[1] + red[3] + red[5] + red[7]) * (1.f/256.f);
        nmi[0] = m;
        nmi[1] = rsqrtf(ms - m*m + 1e-4f);
      }
      __syncthreads();
      if (tid < 64)
        y_out[((size_t)b*TD + (t-1))*UU + q*64 + tid] =
            (cat[768 + q*64 + tid] - nmi[0]) * nmi[1];
    }

    // ---- barrier A poll ----
    if (tid == 0){
      while (__hip_atomic_load(cptr, __ATOMIC_RELAXED, __HIP_MEMORY_SCOPE_SYSTEM) < bar)
        __builtin_amdgcn_s_sleep(2);
    }
    __syncthreads();

    // ---- merge ctx ----
    if (tid < 512){
      float l0 = gload(&l_g[b*4+0]), l1 = gload(&l_g[b*4+1]);
      float l2 = gload(&l_g[b*4+2]), l3 = gload(&l_g[b*4+3]);
      float linv = frcp_(l0 + l1 + l2 + l3);
      float s0 = gload(&pctx_g[((size_t)(b*4+0))*512 + tid])
               + gload(&pctx_g[((size_t)(b*4+1))*512 + tid])
               + gload(&pctx_g[((size_t)(b*4+2))*512 + tid])
               + gload(&pctx_g[((size_t)(b*4+3))*512 + tid]);
      cat[256 + tid] = s0 * linv;
    }
    __syncthreads();

    // ---- gate ctx-rows (k 256..767): half from prefetch regs, half loaded ----
    {
      const int c = tid & 31, kg = tid >> 5;
      const uint4* kp = (const uint4*)KRP + ((size_t)q*1024 + 256 + kg*16)*32 + c;
      float a0=0.f,a1=0.f,a2=0.f,a3=0.f,a4=0.f,a5=0.f,a6=0.f,a7=0.f;
      #pragma unroll
      for (int i = 0; i < 8; ++i){
        uint4 w = pf[i];
        float ck = cat[256 + kg*16 + i];
        a0 += ck*bflo(w.x); a1 += ck*bfhi(w.x);
        a2 += ck*bflo(w.y); a3 += ck*bfhi(w.y);
        a4 += ck*bflo(w.z); a5 += ck*bfhi(w.z);
        a6 += ck*bflo(w.w); a7 += ck*bfhi(w.w);
      }
      #pragma unroll 4
      for (int i = 8; i < 16; ++i){
        uint4 w = kp[(size_t)i*32];
        float ck = cat[256 + kg*16 + i];
        a0 += ck*bflo(w.x); a1 += ck*bfhi(w.x);
        a2 += ck*bflo(w.y); a3 += ck*bfhi(w.y);
        a4 += ck*bflo(w.z); a5 += ck*bfhi(w.z);
        a6 += ck*bflo(w.w); a7 += ck*bfhi(w.w);
      }
      a0 += __shfl_xor(a0, 32); a1 += __shfl_xor(a1, 32);
      a2 += __shfl_xor(a2, 32); a3 += __shfl_xor(a3, 32);
      a4 += __shfl_xor(a4, 32); a5 += __shfl_xor(a5, 32);
      a6 += __shfl_xor(a6, 32); a7 += __shfl_xor(a7, 32);
      float* zb = zbuf[t&1];
      if (lane < 32){
        atomicAdd(&zb[c*8+0], a0); atomicAdd(&zb[c*8+1], a1);
        atomicAdd(&zb[c*8+2], a2); atomicAdd(&zb[c*8+3], a3);
        atomicAdd(&zb[c*8+4], a4); atomicAdd(&zb[c*8+5], a5);
        atomicAdd(&zb[c*8+6], a6); atomicAdd(&zb[c*8+7], a7);
      }
    }
    __syncthreads();

    // ---- LSTM pointwise (keras i,f,g,o), export h slice ----
    if (tid < 64){
      const int jj = q*64 + tid;
      const float* zb = zbuf[t&1];
      float zi = zb[tid]       + gate_b[jj];
      float zf = zb[64 + tid]  + gate_b[256 + jj];
      float zg = zb[128 + tid] + gate_b[512 + jj];
      float zo = zb[192 + tid] + gate_b[768 + jj];
      float cn = sigmoid_fast(zf) * c_lds[tid] + sigmoid_fast(zi) * tanh_fast(zg);
      c_lds[tid] = cn;
      gstore(&h_g[(size_t)b*UU + jj], sigmoid_fast(zo) * tanh_fast(cn));
    }
    // park x_{t+1} (loaded at loop top) into cat[0..256)
    if (t < TD-1 && tid >= 512 && tid < 768) cat[tid - 512] = xnext;
    drain_stores();
    __syncthreads();
    // ---- barrier B signal (poll deferred: x-rows of t+1 hide it) ----
    bar += 4;
    if (tid == 0)
      __hip_atomic_fetch_add(cptr, 1u, __ATOMIC_RELAXED, __HIP_MEMORY_SCOPE_SYSTEM);

    // ---- B-window: gate x-rows for t+1 (k 0..255), needs only x_{t+1} ----
    if (t < TD-1)
      gate_accum<8>(KRP, cat, zbuf[(t+1)&1], q, 0, tid, lane);

    // ---- barrier B poll ----
    if (tid == 0){
      while (__hip_atomic_load(cptr, __ATOMIC_RELAXED, __HIP_MEMORY_SCOPE_SYSTEM) < bar)
        __builtin_amdgcn_s_sleep(2);
    }
    __syncthreads();

    if (tid < 256) cat[768 + tid] = gload(&h_g[(size_t)b*UU + tid]);
    __syncthreads();

    // ---- s_{t+1} = h_t @ Wa + Wa_b (register-resident Wab, pure LDS+VALU) ----
    if (t < TD - 1){
      {
        const int c = tid & 31, kg = tid >> 5;  // u-chunk (8 u), k-group (8 k)
        float a0=0.f,a1=0.f,a2=0.f,a3=0.f,a4=0.f,a5=0.f,a6=0.f,a7=0.f;
        #pragma unroll
        for (int i = 0; i < 8; ++i){
          uint4 w = wab[i];
          float hk = cat[768 + kg*8 + i];
          a0 += hk*bflo(w.x); a1 += hk*bfhi(w.x);
          a2 += hk*bflo(w.y); a3 += hk*bfhi(w.y);
          a4 += hk*bflo(w.z); a5 += hk*bfhi(w.z);
          a6 += hk*bflo(w.w); a7 += hk*bfhi(w.w);
        }
        a0 += __shfl_xor(a0, 32); a1 += __shfl_xor(a1, 32);
        a2 += __shfl_xor(a2, 32); a3 += __shfl_xor(a3, 32);
        a4 += __shfl_xor(a4, 32); a5 += __shfl_xor(a5, 32);
        a6 += __shfl_xor(a6, 32); a7 += __shfl_xor(a7, 32);
        if (lane < 32){
          atomicAdd(&s_acc[c*8+0], a0); atomicAdd(&s_acc[c*8+1], a1);
          atomicAdd(&s_acc[c*8+2], a2); atomicAdd(&s_acc[c*8+3], a3);
          atomicAdd(&s_acc[c*8+4], a4); atomicAdd(&s_acc[c*8+5], a5);
          atomicAdd(&s_acc[c*8+6], a6); atomicAdd(&s_acc[c*8+7], a7);
        }
      }
      __syncthreads();
      if (tid < 256) sva[tid].x = Wa_b[tid] + s_acc[tid];
    }
    __syncthreads();
  }

  // ---- epilogue: y_{TD-1} = whatever_norm(h_{TD-1}) ----
  {
    if (tid < 256){
      float hv = cat[768 + tid];
      float s1 = hv, s2 = hv*hv;
      #pragma unroll
      for (int o = 32; o > 0; o >>= 1){ s1 += __shfl_xor(s1, o); s2 += __shfl_xor(s2, o); }
      if (lane == 0){ red[wave*2] = s1; red[wave*2 + 1] = s2; }
    }
    __syncthreads();
    if (tid == 0){
      float m  = (red[0] + red[2] + red[4] + red[6]) * (1.f/256.f);
      float ms = (red[1] + red[3] + red[5] + red[7]) * (1.f/256.f);
      nmi[0] = m;
      nmi[1] = rsqrtf(ms - m*m + 1e-4f);
    }
    __syncthreads();
    if (tid < 64)
      y_out[((size_t)b*TD + (TD-1))*UU + q*64 + tid] =
          (cat[768 + q*64 + tid] - nmi[0]) * nmi[1];
  }
}

// ---------- head: norm(norm(y2@m1+b)@m2+b)@dW+db -> softmax ----------
__global__ __launch_bounds__(256) void head_kernel(const float* __restrict__ y2,
    const float* __restrict__ m1W, const float* __restrict__ m1b,
    const float* __restrict__ m2W, const float* __restrict__ m2b,
    const float* __restrict__ dW, const float* __restrict__ db,
    float* __restrict__ out){
  __shared__ __align__(16) float aT[256*20];
  __shared__ float t_lds[16*256];
  __shared__ float zl[16*64];
  __shared__ float mi[32];
  const int row0 = blockIdx.x * 16;
  const int tid = threadIdx.x;
  for (int it = 0; it < 16; ++it){
    int idx = tid + 256*it;
    int r = idx >> 8, k = idx & 255;
    aT[k*20 + r] = y2[(size_t)(row0 + r)*UU + k];
  }
  __syncthreads();

  #pragma unroll 1
  for (int pass = 0; pass < 2; ++pass){
    const float* Wp = pass ? m2W : m1W;
    const float* bp = pass ? m2b : m1b;
    const int j = tid;
    float bj = bp[j];
    float acc[16];
    #pragma unroll
    for (int r = 0; r < 16; ++r) acc[r] = bj;
    for (int k = 0; k < 256; ++k){
      float w = Wp[(size_t)k*UU + j];
      const float4* a4 = (const float4*)(aT + k*20);
      float4 q0 = a4[0], q1 = a4[1], q2 = a4[2], q3 = a4[3];
      acc[0]+=q0.x*w;  acc[1]+=q0.y*w;  acc[2]+=q0.z*w;  acc[3]+=q0.w*w;
      acc[4]+=q1.x*w;  acc[5]+=q1.y*w;  acc[6]+=q1.z*w;  acc[7]+=q1.w*w;
      acc[8]+=q2.x*w;  acc[9]+=q2.y*w;  acc[10]+=q2.z*w; acc[11]+=q2.w*w;
      acc[12]+=q3.x*w; acc[13]+=q3.y*w; acc[14]+=q3.z*w; acc[15]+=q3.w*w;
    }
    #pragma unroll
    for (int r = 0; r < 16; ++r) t_lds[r*256 + j] = acc[r];
    __syncthreads();
    {
      int r = tid >> 4, sg = tid & 15;
      float s1 = 0.f, s2 = 0.f;
      for (int c = 0; c < 16; ++c){
        float v = t_lds[r*256 + sg*16 + c];
        s1 += v; s2 += v*v;
      }
      for (int o = 1; o < 16; o <<= 1){ s1 += __shfl_xor(s1, o); s2 += __shfl_xor(s2, o); }
      if (sg == 0){
        float m = s1 * (1.f/256.f);
        float vv = s2 * (1.f/256.f) - m*m;
        mi[r*2] = m; mi[r*2+1] = rsqrtf(vv + 1e-4f);
      }
    }
    __syncthreads();
    {
      const int j2 = tid;
      #pragma unroll
      for (int r = 0; r < 16; ++r)
        aT[j2*20 + r] = (t_lds[r*256 + j2] - mi[r*2]) * mi[r*2+1];
    }
    __syncthreads();
  }

  for (int i = tid; i < 1024; i += 256) zl[i] = 0.f;
  __syncthreads();
  {
    const int j = tid & 63, kq = tid >> 6;
    float acc[16];
    #pragma unroll
    for (int r = 0; r < 16; ++r) acc[r] = 0.f;
    for (int k = 0; k < 64; ++k){
      float w = dW[(size_t)(kq*64 + k)*64 + j];
      const float4* a4 = (const float4*)(aT + (kq*64 + k)*20);
      float4 q0 = a4[0], q1 = a4[1], q2 = a4[2], q3 = a4[3];
      acc[0]+=q0.x*w;  acc[1]+=q0.y*w;  acc[2]+=q0.z*w;  acc[3]+=q0.w*w;
      acc[4]+=q1.x*w;  acc[5]+=q1.y*w;  acc[6]+=q1.z*w;  acc[7]+=q1.w*w;
      acc[8]+=q2.x*w;  acc[9]+=q2.y*w;  acc[10]+=q2.z*w; acc[11]+=q2.w*w;
      acc[12]+=q3.x*w; acc[13]+=q3.y*w; acc[14]+=q3.z*w; acc[15]+=q3.w*w;
    }
    #pragma unroll
    for (int r = 0; r < 16; ++r) atomicAdd(&zl[r*64 + j], acc[r]);
  }
  __syncthreads();
  if (tid < 16){
    const int r = tid;
    float mx = -1e30f;
    for (int j = 0; j < 64; ++j){ float v = zl[r*64 + j] + db[j]; zl[r*64 + j] = v; mx = fmaxf(mx, v); }
    float s = 0.f;
    for (int j = 0; j < 64; ++j){ float e = fexp2((zl[r*64 + j] - mx) * 1.442695041f); zl[r*64 + j] = e; s += e; }
    mi[r] = frcp_(s);
  }
  __syncthreads();
  for (int it = 0; it < 4; ++it){
    int idx = tid + 256*it;
    int r = idx >> 6, j = idx & 63;
    out[(size_t)(row0 + r)*64 + j] = zl[r*64 + j] * mi[r];
  }
}

// ---------- workspace layout (bytes) ----------
#define OFF_SPEECH 0u
#define OFF_ENC    67108864u
#define OFF_KR     100663296u
#define OFF_WA     102760448u
#define OFF_X1     102891520u
#define OFF_Y1     136445952u
#define OFF_PCTX   170000384u
#define OFF_L      170524672u
#define OFF_H      170528768u
#define OFF_CTR    170594304u

#define DYN_LDS    135168    // 256 rows x 264 ushorts

extern "C" void kernel_launch(void* const* d_in, const int* in_sizes, int n_in,
                              void* d_out, int out_size, void* d_ws, size_t ws_size,
                              hipStream_t stream){
  const float* trans  = (const float*)d_in[0];
  const float* speech = (const float*)d_in[1];
  const float* emb_W  = (const float*)d_in[2];
  const float* emb_b  = (const float*)d_in[3];
  const float* Ua_W[2]  = {(const float*)d_in[4],  (const float*)d_in[13]};
  const float* Ua_b[2]  = {(const float*)d_in[5],  (const float*)d_in[14]};
  const float* Wa_W[2]  = {(const float*)d_in[6],  (const float*)d_in[15]};
  const float* Wa_bv[2] = {(const float*)d_in[7],  (const float*)d_in[16]};
  const float* va_W[2]  = {(const float*)d_in[8],  (const float*)d_in[17]};
  // d_in[9]/d_in[18] = va_b: constant logit shift, softmax-invariant, dropped exactly.
  const float* Kw[2]    = {(const float*)d_in[10], (const float*)d_in[19]};
  const float* Rw[2]    = {(const float*)d_in[11], (const float*)d_in[20]};
  const float* bw[2]    = {(const float*)d_in[12], (const float*)d_in[21]};
  const float* m1W = (const float*)d_in[22];
  const float* m1b = (const float*)d_in[23];
  const float* m2W = (const float*)d_in[24];
  const float* m2b = (const float*)d_in[25];
  const float* dW  = (const float*)d_in[26];
  const float* db  = (const float*)d_in[27];

  char* ws = (char*)d_ws;
  unsigned short* speech_bf = (unsigned short*)(ws + OFF_SPEECH);
  unsigned short* enc  = (unsigned short*)(ws + OFF_ENC);
  unsigned short* KRP  = (unsigned short*)(ws + OFF_KR);
  unsigned short* Wab  = (unsigned short*)(ws + OFF_WA);
  float* x1   = (float*)(ws + OFF_X1);
  float* y1   = (float*)(ws + OFF_Y1);
  float* pctx = (float*)(ws + OFF_PCTX);
  float* lg   = (float*)(ws + OFF_L);
  float* hg   = (float*)(ws + OFF_H);
  unsigned int* ctr = (unsigned int*)(ws + OFF_CTR);
  float* y2 = x1;   // x1 dead after scan1 consumes it

  hipFuncSetAttribute((const void*)scan_kernel,
                      hipFuncAttributeMaxDynamicSharedMemorySize, DYN_LDS);

  hipMemsetAsync(ctr, 0, 4096, stream);
  pack_bf16v<<<4096, 256, 0, stream>>>(speech, speech_bf, B*TE*EE/4);
  emb_gemm<<<2048, 256, 0, stream>>>(trans, emb_W, emb_b, x1);

  for (int L = 0; L < 2; ++L){
    enc_gemm<<<4096, 256, 0, stream>>>(speech, Ua_W[L], Ua_b[L], enc);
    pack_KRP<<<4096, 256, 0, stream>>>(Kw[L], Rw[L], KRP);
    pack_bf16v<<<64, 256, 0, stream>>>(Wa_W[L], Wab, UU*UU/4);
    if (L == 1) hipMemsetAsync(ctr, 0, 4096, stream);
    scan_kernel<<<256, 1024, DYN_LDS, stream>>>(L == 0 ? x1 : y1, L == 0 ? y1 : y2,
        enc, speech_bf, KRP, Wab, Wa_bv[L], va_W[L], bw[L], pctx, lg, hg, ctr);
  }

  head_kernel<<<2048, 256, 0, stream>>>(y2, m1W, m1b, m2W, m2b, dW, db, (float*)d_out);
  (void)in_sizes; (void)n_in; (void)out_size; (void)ws_size;
}

// Round 4
// 65586.395 us; speedup vs baseline: 1.2154x; 1.2107x over previous
//
#include <hip/hip_runtime.h>
#include <hip/hip_bf16.h>
#include <stdint.h>

#define B  64
#define TD 512
#define TE 1024
#define EE 512
#define UU 256

// ---------- numeric helpers ----------
__device__ __forceinline__ float fexp2(float x){ return __builtin_amdgcn_exp2f(x); }
__device__ __forceinline__ float frcp_(float x){ return __builtin_amdgcn_rcpf(x); }
__device__ __forceinline__ float tanh_fast(float x){
  float e = fexp2(x * 2.885390082f);
  return 1.f - 2.f * frcp_(e + 1.f);
}
__device__ __forceinline__ float sigmoid_fast(float x){
  return frcp_(1.f + fexp2(-1.442695041f * x));
}
__device__ __forceinline__ unsigned short f2bf(float f){
  unsigned int u = __float_as_uint(f);
  u = (u + 0x7fffu + ((u >> 16) & 1u)) >> 16;   // RNE
  return (unsigned short)u;
}
__device__ __forceinline__ float bflo(unsigned int w){ return __uint_as_float(w << 16); }
__device__ __forceinline__ float bfhi(unsigned int w){ return __uint_as_float(w & 0xffff0000u); }

// Cross-XCD comm WITHOUT cache flushes: relaxed system-scope ops lower to
// global_load/store/atomic with sc0 sc1 (bypass L1/L2, coherent at L3) and
// never emit buffer_inv/buffer_wbl2 -> L2 stays hot for speech/KR.
__device__ __forceinline__ void gstore(float* p, float v){
  __hip_atomic_store(p, v, __ATOMIC_RELAXED, __HIP_MEMORY_SCOPE_SYSTEM);
}
__device__ __forceinline__ float gload(const float* p){
  return __hip_atomic_load(p, __ATOMIC_RELAXED, __HIP_MEMORY_SCOPE_SYSTEM);
}
__device__ __forceinline__ void drain_stores(){
  __atomic_signal_fence(__ATOMIC_SEQ_CST);
  __builtin_amdgcn_s_waitcnt(0);
  __atomic_signal_fence(__ATOMIC_SEQ_CST);
}

// Gate partial GEMV over k-range [k0, k0+32*NITER) of this WG's KRP slice,
// accumulating into LDS zb[256] (jj = (tid&31)*8 + i). x-rows (k0=0) run one
// step EARLY to hide barrier B; h-rows (k0=768) run in the barrier-A window;
// ctx-rows (k0=256, NITER=16) run post-merge.
template<int NITER>
__device__ __forceinline__ void gate_accum(const unsigned short* __restrict__ KRP,
    const float* catp, float* zb, int q, int k0, int tid, int lane){
  const int c = tid & 31, kg = tid >> 5;
  const uint4* kp = (const uint4*)KRP + ((size_t)q*1024 + k0 + kg*NITER)*32 + c;
  float a0=0.f,a1=0.f,a2=0.f,a3=0.f,a4=0.f,a5=0.f,a6=0.f,a7=0.f;
  #pragma unroll 4
  for (int i = 0; i < NITER; ++i){
    uint4 w = kp[(size_t)i*32];
    float ck = catp[k0 + kg*NITER + i];
    a0 += ck*bflo(w.x); a1 += ck*bfhi(w.x);
    a2 += ck*bflo(w.y); a3 += ck*bfhi(w.y);
    a4 += ck*bflo(w.z); a5 += ck*bfhi(w.z);
    a6 += ck*bflo(w.w); a7 += ck*bfhi(w.w);
  }
  a0 += __shfl_xor(a0, 32); a1 += __shfl_xor(a1, 32);
  a2 += __shfl_xor(a2, 32); a3 += __shfl_xor(a3, 32);
  a4 += __shfl_xor(a4, 32); a5 += __shfl_xor(a5, 32);
  a6 += __shfl_xor(a6, 32); a7 += __shfl_xor(a7, 32);
  if (lane < 32){
    atomicAdd(&zb[c*8+0], a0); atomicAdd(&zb[c*8+1], a1);
    atomicAdd(&zb[c*8+2], a2); atomicAdd(&zb[c*8+3], a3);
    atomicAdd(&zb[c*8+4], a4); atomicAdd(&zb[c*8+5], a5);
    atomicAdd(&zb[c*8+6], a6); atomicAdd(&zb[c*8+7], a7);
  }
}

// ---------- pack kernels ----------
__global__ void pack_bf16v(const float* __restrict__ in, unsigned short* __restrict__ out, int n4){
  int i = blockIdx.x * blockDim.x + threadIdx.x;
  int stride = gridDim.x * blockDim.x;
  for (; i < n4; i += stride){
    float4 v = ((const float4*)in)[i];
    ushort4 o;
    o.x = f2bf(v.x); o.y = f2bf(v.y); o.z = f2bf(v.z); o.w = f2bf(v.w);
    ((ushort4*)out)[i] = o;
  }
}

// KRP[q][k][jj]: per-WG-contiguous gate weights. jj in [0,256) maps to
// logical column J = (jj>>6)*256 + q*64 + (jj&63); rows 0..767 = K, 768..1023 = R.
// Total elements = 4*1024*256 = 1,048,576 -> grid MUST be 4096 x 256 (R4 bug: 8192
// overran the 2 MB buffer and trashed Wab/x1).
__global__ void pack_KRP(const float* __restrict__ K, const float* __restrict__ R,
                         unsigned short* __restrict__ KRP){
  int idx = blockIdx.x * 256 + threadIdx.x;    // 4096 blocks -> 1M exactly
  int q  = idx >> 18;
  int k  = (idx >> 8) & 1023;
  int jj = idx & 255;
  int J  = (jj >> 6)*256 + q*64 + (jj & 63);
  float v = (k < 768) ? K[(size_t)k*1024 + J] : R[(size_t)(k - 768)*1024 + J];
  KRP[idx] = f2bf(v);
}

// ---------- secrets = trans @ emb_W + emb_b : [32768,64]@[64,256] ----------
__global__ __launch_bounds__(256) void emb_gemm(const float* __restrict__ trans,
    const float* __restrict__ W, const float* __restrict__ bias, float* __restrict__ out){
  __shared__ __align__(16) float aT[64*20];
  const int row0 = blockIdx.x * 16;
  const int tid = threadIdx.x;
  {
    int r = tid >> 6, k = tid & 63;
    for (int rr = r; rr < 16; rr += 4)
      aT[k*20 + rr] = trans[(size_t)(row0 + rr)*64 + k];
  }
  __syncthreads();
  const int j = tid;
  float bj = bias[j];
  float acc[16];
  #pragma unroll
  for (int r = 0; r < 16; ++r) acc[r] = bj;
  for (int k = 0; k < 64; ++k){
    float w = W[(size_t)k*UU + j];
    const float4* a4 = (const float4*)(aT + k*20);
    float4 q0 = a4[0], q1 = a4[1], q2 = a4[2], q3 = a4[3];
    acc[0]+=q0.x*w;  acc[1]+=q0.y*w;  acc[2]+=q0.z*w;  acc[3]+=q0.w*w;
    acc[4]+=q1.x*w;  acc[5]+=q1.y*w;  acc[6]+=q1.z*w;  acc[7]+=q1.w*w;
    acc[8]+=q2.x*w;  acc[9]+=q2.y*w;  acc[10]+=q2.z*w; acc[11]+=q2.w*w;
    acc[12]+=q3.x*w; acc[13]+=q3.y*w; acc[14]+=q3.z*w; acc[15]+=q3.w*w;
  }
  #pragma unroll
  for (int r = 0; r < 16; ++r)
    out[(size_t)(row0 + r)*UU + j] = acc[r];
}

// ---------- enc = speech @ Ua + Ua_b, stored bf16 [B][TE][U] ----------
__global__ __launch_bounds__(256) void enc_gemm(const float* __restrict__ speech,
    const float* __restrict__ Ua, const float* __restrict__ Uab,
    unsigned short* __restrict__ enc){
  __shared__ __align__(16) float aT[512*20];
  const int wg = blockIdx.x;
  const int b = wg >> 6, tb = (wg & 63) * 16;
  const int tid = threadIdx.x;
  const float* sp = speech + ((size_t)b*TE + tb)*EE;
  for (int it = 0; it < 32; ++it){
    int idx = tid + 256*it;
    int te = idx >> 9, e = idx & 511;
    aT[e*20 + te] = sp[(size_t)te*EE + e];
  }
  __syncthreads();
  const int j = tid;
  float bj = Uab[j];
  float acc[16];
  #pragma unroll
  for (int r = 0; r < 16; ++r) acc[r] = bj;
  const float* up = Ua + j;
  for (int e = 0; e < 512; ++e){
    float w = up[(size_t)e*UU];
    const float4* a4 = (const float4*)(aT + e*20);
    float4 q0 = a4[0], q1 = a4[1], q2 = a4[2], q3 = a4[3];
    acc[0]+=q0.x*w;  acc[1]+=q0.y*w;  acc[2]+=q0.z*w;  acc[3]+=q0.w*w;
    acc[4]+=q1.x*w;  acc[5]+=q1.y*w;  acc[6]+=q1.z*w;  acc[7]+=q1.w*w;
    acc[8]+=q2.x*w;  acc[9]+=q2.y*w;  acc[10]+=q2.z*w; acc[11]+=q2.w*w;
    acc[12]+=q3.x*w; acc[13]+=q3.y*w; acc[14]+=q3.z*w; acc[15]+=q3.w*w;
  }
  unsigned short* op = enc + ((size_t)b*TE + tb)*UU + j;
  #pragma unroll
  for (int r = 0; r < 16; ++r) op[(size_t)r*UU] = f2bf(acc[r]);
}

// ---------- persistent attention-LSTM scan ----------
// grid 256 = 64 batches x 4 WGs; 1024 threads. enc slice persisted in dynamic
// LDS (132 KB, stride 264 ushorts). All big streams are uint4 rolled loops.
// 4-WG barriers: relaxed system-scope counter (no cache flushes).
//
// R5: gate GEMV split by dependency (x-rows early / h-rows in A-window /
//     ctx-rows post-merge); conflict-free P1 stores.
// R6: Wab register-resident; y-norm in A-window, distributed across WGs.
// R7 FAILED: __launch_bounds__(1024,4) left the allocator at 64 VGPRs
//     (VGPR_Count 64, FETCH unchanged) -> wab[8] still spilled to scratch,
//     reloaded from VRAM every step (FETCH +17.3 GB == 128 B/thread/step).
// R8: (a) amdgpu_waves_per_eu(4,4) pins the occupancy TARGET (min AND max)
//     at 4 waves/EU -> register budget 128. LDS caps us at 1 WG/CU anyway,
//     so nothing is lost. (b) pf[8] ctx-prefetch dropped (-32 VGPRs at the
//     worst point): marginal benefit (KRP is L2-hot), and without it even a
//     64-reg budget fits the live set, so the round is safe either way.
__global__ __launch_bounds__(1024)
__attribute__((amdgpu_waves_per_eu(4, 4)))
void scan_kernel(
    const float* __restrict__ x_seq, float* __restrict__ y_out,
    const unsigned short* __restrict__ enc, const unsigned short* __restrict__ speech,
    const unsigned short* __restrict__ KRP, const unsigned short* __restrict__ Wab,
    const float* __restrict__ Wa_b, const float* __restrict__ va,
    const float* __restrict__ gate_b,
    float* __restrict__ pctx_g, float* __restrict__ l_g, float* __restrict__ h_g,
    unsigned int* __restrict__ ctr){
  extern __shared__ __align__(16) unsigned short enc_l[];   // [256][264] = 132 KB
  __shared__ float2 sva[256];        // (s[u], va[u])
  __shared__ float cat[1024];        // [0,256)=x_t  [256,768)=ctx  [768,1024)=h_{t-1}
  __shared__ float c_lds[64];
  __shared__ float lds_logit4[1024]; // [4 u-quarters][256 te]
  __shared__ float p_lds[256];
  __shared__ float lds_pctx[512];
  __shared__ float zbuf[2][256];     // gate accumulators, ping-pong over t
  __shared__ float s_acc[256];
  __shared__ float red[32];
  __shared__ float nmi[2];

  const int tid = threadIdx.x;
  const int wg = blockIdx.x;
  const int b = wg >> 2, q = wg & 3;
  const int lane = tid & 63, wave = tid >> 6;
  unsigned int bar = 0;
  unsigned int* cptr = &ctr[b*16];

  // one-time: stage this WG's enc slice (256 te x 256 u bf16) into LDS
  {
    const uint4* ep4 = (const uint4*)(enc + ((size_t)b*TE + q*256)*UU);
    #pragma unroll
    for (int i = 0; i < 8; ++i){
      int idx = tid + 1024*i;                   // 8192 uint4
      int te_l = idx >> 5, ch = idx & 31;
      uint4 v = ep4[(size_t)te_l*32 + ch];
      *(uint4*)(enc_l + (size_t)te_l*264 + ch*8) = v;
    }
  }
  if (tid < 256){ sva[tid] = make_float2(Wa_b[tid], va[tid]); cat[768 + tid] = 0.f;
                  zbuf[0][tid] = 0.f; zbuf[1][tid] = 0.f; }
  if (tid < 64) c_lds[tid] = 0.f;
  if (tid >= 512 && tid < 768)
    cat[tid - 512] = x_seq[((size_t)b*TD + 0)*UU + (tid - 512)];

  // one-time: Wab weights resident in registers (128 B/thread = 8 uint4)
  uint4 wab[8];
  {
    const int c = tid & 31, kg = tid >> 5;
    const uint4* wp = (const uint4*)Wab + (size_t)(kg*8)*32 + c;
    #pragma unroll
    for (int i = 0; i < 8; ++i) wab[i] = wp[(size_t)i*32];
  }
  __syncthreads();
  // prologue: x-rows gate contribution for t=0
  gate_accum<8>(KRP, cat, zbuf[0], q, 0, tid, lane);

  for (int t = 0; t < TD; ++t){
    // ---- loop top: zero scratch, issue x_{t+1} load (held in register) ----
    if (tid < 512) lds_pctx[tid] = 0.f;
    if (tid < 256){ zbuf[(t+1)&1][tid] = 0.f; s_acc[tid] = 0.f; }
    float xnext = 0.f;
    if (t < TD-1 && tid >= 512 && tid < 768)
      xnext = x_seq[((size_t)b*TD + t + 1)*UU + (tid - 512)];
    __syncthreads();

    // ---- P1: attention logits from LDS enc (conflict-free partial stores) ----
    {
      const int g = wave & 3, r = wave >> 2;
      const int te_l = g*64 + lane;             // local te 0..255
      const unsigned short* ep = enc_l + (size_t)te_l*264 + r*64;
      float acc = 0.f;
      #pragma unroll
      for (int c = 0; c < 8; ++c){
        uint4 v = *(const uint4*)(ep + c*8);
        const int ub = r*64 + c*8;
        unsigned int wv[4] = {v.x, v.y, v.z, v.w};
        #pragma unroll
        for (int i = 0; i < 4; ++i){
          float2 s0 = sva[ub + 2*i];
          float2 s1 = sva[ub + 2*i + 1];
          acc += s0.y * tanh_fast(s0.x + bflo(wv[i]));
          acc += s1.y * tanh_fast(s1.x + bfhi(wv[i]));
        }
      }
      lds_logit4[r*256 + te_l] = acc;           // unique (r,te_l) per thread
    }
    __syncthreads();

    // ---- P2: p = exp(logit), wave partial sums ----
    if (tid < 256){
      float lg = lds_logit4[tid] + lds_logit4[256 + tid]
               + lds_logit4[512 + tid] + lds_logit4[768 + tid];
      float p = fexp2(lg * 1.442695041f);
      p_lds[tid] = p;
      float s = p;
      #pragma unroll
      for (int o = 32; o > 0; o >>= 1) s += __shfl_xor(s, o);
      if (lane == 0) red[wave] = s;
    }
    __syncthreads();

    // ---- P3: partial ctx = sum_te p[te]*speech[te][:]  (uint4 stream) ----
    {
      const int c = tid & 63, tg = tid >> 6;    // e-chunk (8 e), te-group (16 te)
      const uint4* sp4 = (const uint4*)speech + ((size_t)b*TE + q*256 + tg*16)*64 + c;
      float a0=0.f,a1=0.f,a2=0.f,a3=0.f,a4=0.f,a5=0.f,a6=0.f,a7=0.f;
      #pragma unroll 4
      for (int i = 0; i < 16; ++i){
        uint4 w = sp4[(size_t)i*64];
        float p = p_lds[tg*16 + i];
        a0 += p*bflo(w.x); a1 += p*bfhi(w.x);
        a2 += p*bflo(w.y); a3 += p*bfhi(w.y);
        a4 += p*bflo(w.z); a5 += p*bfhi(w.z);
        a6 += p*bflo(w.w); a7 += p*bfhi(w.w);
      }
      atomicAdd(&lds_pctx[c*8+0], a0); atomicAdd(&lds_pctx[c*8+1], a1);
      atomicAdd(&lds_pctx[c*8+2], a2); atomicAdd(&lds_pctx[c*8+3], a3);
      atomicAdd(&lds_pctx[c*8+4], a4); atomicAdd(&lds_pctx[c*8+5], a5);
      atomicAdd(&lds_pctx[c*8+6], a6); atomicAdd(&lds_pctx[c*8+7], a7);
    }
    __syncthreads();
    if (tid < 512) gstore(&pctx_g[((size_t)(b*4 + q))*512 + tid], lds_pctx[tid]);
    if (tid == 0)  gstore(&l_g[b*4 + q], red[0] + red[1] + red[2] + red[3]);
    drain_stores();
    __syncthreads();
    // ---- barrier A signal (poll deferred: window work hides it) ----
    bar += 4;
    if (tid == 0)
      __hip_atomic_fetch_add(cptr, 1u, __ATOMIC_RELAXED, __HIP_MEMORY_SCOPE_SYSTEM);

    // ---- A-window 1: gate h-rows (k 768..1023), needs only h_{t-1} ----
    gate_accum<8>(KRP, cat, zbuf[t&1], q, 768, tid, lane);

    // ---- A-window 2: y_{t-1} = whatever_norm(h_{t-1}) (off critical path;
    //      all WGs reduce redundantly, each writes its own 64-wide slice) ----
    if (t > 0){
      if (tid < 256){
        float hv = cat[768 + tid];
        float s1 = hv, s2 = hv*hv;
        #pragma unroll
        for (int o = 32; o > 0; o >>= 1){ s1 += __shfl_xor(s1, o); s2 += __shfl_xor(s2, o); }
        if (lane == 0){ red[wave*2] = s1; red[wave*2 + 1] = s2; }
      }
      __syncthreads();
      if (tid == 0){
        float m  = (red[0] + red[2] + red[4] + red[6]) * (1.f/256.f);
        float ms = (red[1] + red[3] + red[5] + red[7]) * (1.f/256.f);
        nmi[0] = m;
        nmi[1] = rsqrtf(ms - m*m + 1e-4f);
      }
      __syncthreads();
      if (tid < 64)
        y_out[((size_t)b*TD + (t-1))*UU + q*64 + tid] =
            (cat[768 + q*64 + tid] - nmi[0]) * nmi[1];
    }

    // ---- barrier A poll ----
    if (tid == 0){
      while (__hip_atomic_load(cptr, __ATOMIC_RELAXED, __HIP_MEMORY_SCOPE_SYSTEM) < bar)
        __builtin_amdgcn_s_sleep(2);
    }
    __syncthreads();

    // ---- merge ctx ----
    if (tid < 512){
      float l0 = gload(&l_g[b*4+0]), l1 = gload(&l_g[b*4+1]);
      float l2 = gload(&l_g[b*4+2]), l3 = gload(&l_g[b*4+3]);
      float linv = frcp_(l0 + l1 + l2 + l3);
      float s0 = gload(&pctx_g[((size_t)(b*4+0))*512 + tid])
               + gload(&pctx_g[((size_t)(b*4+1))*512 + tid])
               + gload(&pctx_g[((size_t)(b*4+2))*512 + tid])
               + gload(&pctx_g[((size_t)(b*4+3))*512 + tid]);
      cat[256 + tid] = s0 * linv;
    }
    __syncthreads();

    // ---- gate ctx-rows (k 256..767): plain 16-iter uint4 stream ----
    gate_accum<16>(KRP, cat, zbuf[t&1], q, 256, tid, lane);
    __syncthreads();

    // ---- LSTM pointwise (keras i,f,g,o), export h slice ----
    if (tid < 64){
      const int jj = q*64 + tid;
      const float* zb = zbuf[t&1];
      float zi = zb[tid]       + gate_b[jj];
      float zf = zb[64 + tid]  + gate_b[256 + jj];
      float zg = zb[128 + tid] + gate_b[512 + jj];
      float zo = zb[192 + tid] + gate_b[768 + jj];
      float cn = sigmoid_fast(zf) * c_lds[tid] + sigmoid_fast(zi) * tanh_fast(zg);
      c_lds[tid] = cn;
      gstore(&h_g[(size_t)b*UU + jj], sigmoid_fast(zo) * tanh_fast(cn));
    }
    // park x_{t+1} (loaded at loop top) into cat[0..256)
    if (t < TD-1 && tid >= 512 && tid < 768) cat[tid - 512] = xnext;
    drain_stores();
    __syncthreads();
    // ---- barrier B signal (poll deferred: x-rows of t+1 hide it) ----
    bar += 4;
    if (tid == 0)
      __hip_atomic_fetch_add(cptr, 1u, __ATOMIC_RELAXED, __HIP_MEMORY_SCOPE_SYSTEM);

    // ---- B-window: gate x-rows for t+1 (k 0..255), needs only x_{t+1} ----
    if (t < TD-1)
      gate_accum<8>(KRP, cat, zbuf[(t+1)&1], q, 0, tid, lane);

    // ---- barrier B poll ----
    if (tid == 0){
      while (__hip_atomic_load(cptr, __ATOMIC_RELAXED, __HIP_MEMORY_SCOPE_SYSTEM) < bar)
        __builtin_amdgcn_s_sleep(2);
    }
    __syncthreads();

    if (tid < 256) cat[768 + tid] = gload(&h_g[(size_t)b*UU + tid]);
    __syncthreads();

    // ---- s_{t+1} = h_t @ Wa + Wa_b (register-resident Wab, pure LDS+VALU) ----
    if (t < TD - 1){
      {
        const int c = tid & 31, kg = tid >> 5;  // u-chunk (8 u), k-group (8 k)
        float a0=0.f,a1=0.f,a2=0.f,a3=0.f,a4=0.f,a5=0.f,a6=0.f,a7=0.f;
        #pragma unroll
        for (int i = 0; i < 8; ++i){
          uint4 w = wab[i];
          float hk = cat[768 + kg*8 + i];
          a0 += hk*bflo(w.x); a1 += hk*bfhi(w.x);
          a2 += hk*bflo(w.y); a3 += hk*bfhi(w.y);
          a4 += hk*bflo(w.z); a5 += hk*bfhi(w.z);
          a6 += hk*bflo(w.w); a7 += hk*bfhi(w.w);
        }
        a0 += __shfl_xor(a0, 32); a1 += __shfl_xor(a1, 32);
        a2 += __shfl_xor(a2, 32); a3 += __shfl_xor(a3, 32);
        a4 += __shfl_xor(a4, 32); a5 += __shfl_xor(a5, 32);
        a6 += __shfl_xor(a6, 32); a7 += __shfl_xor(a7, 32);
        if (lane < 32){
          atomicAdd(&s_acc[c*8+0], a0); atomicAdd(&s_acc[c*8+1], a1);
          atomicAdd(&s_acc[c*8+2], a2); atomicAdd(&s_acc[c*8+3], a3);
          atomicAdd(&s_acc[c*8+4], a4); atomicAdd(&s_acc[c*8+5], a5);
          atomicAdd(&s_acc[c*8+6], a6); atomicAdd(&s_acc[c*8+7], a7);
        }
      }
      __syncthreads();
      if (tid < 256) sva[tid].x = Wa_b[tid] + s_acc[tid];
    }
    __syncthreads();
  }

  // ---- epilogue: y_{TD-1} = whatever_norm(h_{TD-1}) ----
  {
    if (tid < 256){
      float hv = cat[768 + tid];
      float s1 = hv, s2 = hv*hv;
      #pragma unroll
      for (int o = 32; o > 0; o >>= 1){ s1 += __shfl_xor(s1, o); s2 += __shfl_xor(s2, o); }
      if (lane == 0){ red[wave*2] = s1; red[wave*2 + 1] = s2; }
    }
    __syncthreads();
    if (tid == 0){
      float m  = (red[0] + red[2] + red[4] + red[6]) * (1.f/256.f);
      float ms = (red[1] + red[3] + red[5] + red[7]) * (1.f/256.f);
      nmi[0] = m;
      nmi[1] = rsqrtf(ms - m*m + 1e-4f);
    }
    __syncthreads();
    if (tid < 64)
      y_out[((size_t)b*TD + (TD-1))*UU + q*64 + tid] =
          (cat[768 + q*64 + tid] - nmi[0]) * nmi[1];
  }
}

// ---------- head: norm(norm(y2@m1+b)@m2+b)@dW+db -> softmax ----------
__global__ __launch_bounds__(256) void head_kernel(const float* __restrict__ y2,
    const float* __restrict__ m1W, const float* __restrict__ m1b,
    const float* __restrict__ m2W, const float* __restrict__ m2b,
    const float* __restrict__ dW, const float* __restrict__ db,
    float* __restrict__ out){
  __shared__ __align__(16) float aT[256*20];
  __shared__ float t_lds[16*256];
  __shared__ float zl[16*64];
  __shared__ float mi[32];
  const int row0 = blockIdx.x * 16;
  const int tid = threadIdx.x;
  for (int it = 0; it < 16; ++it){
    int idx = tid + 256*it;
    int r = idx >> 8, k = idx & 255;
    aT[k*20 + r] = y2[(size_t)(row0 + r)*UU + k];
  }
  __syncthreads();

  #pragma unroll 1
  for (int pass = 0; pass < 2; ++pass){
    const float* Wp = pass ? m2W : m1W;
    const float* bp = pass ? m2b : m1b;
    const int j = tid;
    float bj = bp[j];
    float acc[16];
    #pragma unroll
    for (int r = 0; r < 16; ++r) acc[r] = bj;
    for (int k = 0; k < 256; ++k){
      float w = Wp[(size_t)k*UU + j];
      const float4* a4 = (const float4*)(aT + k*20);
      float4 q0 = a4[0], q1 = a4[1], q2 = a4[2], q3 = a4[3];
      acc[0]+=q0.x*w;  acc[1]+=q0.y*w;  acc[2]+=q0.z*w;  acc[3]+=q0.w*w;
      acc[4]+=q1.x*w;  acc[5]+=q1.y*w;  acc[6]+=q1.z*w;  acc[7]+=q1.w*w;
      acc[8]+=q2.x*w;  acc[9]+=q2.y*w;  acc[10]+=q2.z*w; acc[11]+=q2.w*w;
      acc[12]+=q3.x*w; acc[13]+=q3.y*w; acc[14]+=q3.z*w; acc[15]+=q3.w*w;
    }
    #pragma unroll
    for (int r = 0; r < 16; ++r) t_lds[r*256 + j] = acc[r];
    __syncthreads();
    {
      int r = tid >> 4, sg = tid & 15;
      float s1 = 0.f, s2 = 0.f;
      for (int c = 0; c < 16; ++c){
        float v = t_lds[r*256 + sg*16 + c];
        s1 += v; s2 += v*v;
      }
      for (int o = 1; o < 16; o <<= 1){ s1 += __shfl_xor(s1, o); s2 += __shfl_xor(s2, o); }
      if (sg == 0){
        float m = s1 * (1.f/256.f);
        float vv = s2 * (1.f/256.f) - m*m;
        mi[r*2] = m; mi[r*2+1] = rsqrtf(vv + 1e-4f);
      }
    }
    __syncthreads();
    {
      const int j2 = tid;
      #pragma unroll
      for (int r = 0; r < 16; ++r)
        aT[j2*20 + r] = (t_lds[r*256 + j2] - mi[r*2]) * mi[r*2+1];
    }
    __syncthreads();
  }

  for (int i = tid; i < 1024; i += 256) zl[i] = 0.f;
  __syncthreads();
  {
    const int j = tid & 63, kq = tid >> 6;
    float acc[16];
    #pragma unroll
    for (int r = 0; r < 16; ++r) acc[r] = 0.f;
    for (int k = 0; k < 64; ++k){
      float w = dW[(size_t)(kq*64 + k)*64 + j];
      const float4* a4 = (const float4*)(aT + (kq*64 + k)*20);
      float4 q0 = a4[0], q1 = a4[1], q2 = a4[2], q3 = a4[3];
      acc[0]+=q0.x*w;  acc[1]+=q0.y*w;  acc[2]+=q0.z*w;  acc[3]+=q0.w*w;
      acc[4]+=q1.x*w;  acc[5]+=q1.y*w;  acc[6]+=q1.z*w;  acc[7]+=q1.w*w;
      acc[8]+=q2.x*w;  acc[9]+=q2.y*w;  acc[10]+=q2.z*w; acc[11]+=q2.w*w;
      acc[12]+=q3.x*w; acc[13]+=q3.y*w; acc[14]+=q3.z*w; acc[15]+=q3.w*w;
    }
    #pragma unroll
    for (int r = 0; r < 16; ++r) atomicAdd(&zl[r*64 + j], acc[r]);
  }
  __syncthreads();
  if (tid < 16){
    const int r = tid;
    float mx = -1e30f;
    for (int j = 0; j < 64; ++j){ float v = zl[r*64 + j] + db[j]; zl[r*64 + j] = v; mx = fmaxf(mx, v); }
    float s = 0.f;
    for (int j = 0; j < 64; ++j){ float e = fexp2((zl[r*64 + j] - mx) * 1.442695041f); zl[r*64 + j] = e; s += e; }
    mi[r] = frcp_(s);
  }
  __syncthreads();
  for (int it = 0; it < 4; ++it){
    int idx = tid + 256*it;
    int r = idx >> 6, j = idx & 63;
    out[(size_t)(row0 + r)*64 + j] = zl[r*64 + j] * mi[r];
  }
}

// ---------- workspace layout (bytes) ----------
#define OFF_SPEECH 0u
#define OFF_ENC    67108864u
#define OFF_KR     100663296u
#define OFF_WA     102760448u
#define OFF_X1     102891520u
#define OFF_Y1     136445952u
#define OFF_PCTX   170000384u
#define OFF_L      170524672u
#define OFF_H      170528768u
#define OFF_CTR    170594304u

#define DYN_LDS    135168    // 256 rows x 264 ushorts

extern "C" void kernel_launch(void* const* d_in, const int* in_sizes, int n_in,
                              void* d_out, int out_size, void* d_ws, size_t ws_size,
                              hipStream_t stream){
  const float* trans  = (const float*)d_in[0];
  const float* speech = (const float*)d_in[1];
  const float* emb_W  = (const float*)d_in[2];
  const float* emb_b  = (const float*)d_in[3];
  const float* Ua_W[2]  = {(const float*)d_in[4],  (const float*)d_in[13]};
  const float* Ua_b[2]  = {(const float*)d_in[5],  (const float*)d_in[14]};
  const float* Wa_W[2]  = {(const float*)d_in[6],  (const float*)d_in[15]};
  const float* Wa_bv[2] = {(const float*)d_in[7],  (const float*)d_in[16]};
  const float* va_W[2]  = {(const float*)d_in[8],  (const float*)d_in[17]};
  // d_in[9]/d_in[18] = va_b: constant logit shift, softmax-invariant, dropped exactly.
  const float* Kw[2]    = {(const float*)d_in[10], (const float*)d_in[19]};
  const float* Rw[2]    = {(const float*)d_in[11], (const float*)d_in[20]};
  const float* bw[2]    = {(const float*)d_in[12], (const float*)d_in[21]};
  const float* m1W = (const float*)d_in[22];
  const float* m1b = (const float*)d_in[23];
  const float* m2W = (const float*)d_in[24];
  const float* m2b = (const float*)d_in[25];
  const float* dW  = (const float*)d_in[26];
  const float* db  = (const float*)d_in[27];

  char* ws = (char*)d_ws;
  unsigned short* speech_bf = (unsigned short*)(ws + OFF_SPEECH);
  unsigned short* enc  = (unsigned short*)(ws + OFF_ENC);
  unsigned short* KRP  = (unsigned short*)(ws + OFF_KR);
  unsigned short* Wab  = (unsigned short*)(ws + OFF_WA);
  float* x1   = (float*)(ws + OFF_X1);
  float* y1   = (float*)(ws + OFF_Y1);
  float* pctx = (float*)(ws + OFF_PCTX);
  float* lg   = (float*)(ws + OFF_L);
  float* hg   = (float*)(ws + OFF_H);
  unsigned int* ctr = (unsigned int*)(ws + OFF_CTR);
  float* y2 = x1;   // x1 dead after scan1 consumes it

  hipFuncSetAttribute((const void*)scan_kernel,
                      hipFuncAttributeMaxDynamicSharedMemorySize, DYN_LDS);

  hipMemsetAsync(ctr, 0, 4096, stream);
  pack_bf16v<<<4096, 256, 0, stream>>>(speech, speech_bf, B*TE*EE/4);
  emb_gemm<<<2048, 256, 0, stream>>>(trans, emb_W, emb_b, x1);

  for (int L = 0; L < 2; ++L){
    enc_gemm<<<4096, 256, 0, stream>>>(speech, Ua_W[L], Ua_b[L], enc);
    pack_KRP<<<4096, 256, 0, stream>>>(Kw[L], Rw[L], KRP);
    pack_bf16v<<<64, 256, 0, stream>>>(Wa_W[L], Wab, UU*UU/4);
    if (L == 1) hipMemsetAsync(ctr, 0, 4096, stream);
    scan_kernel<<<256, 1024, DYN_LDS, stream>>>(L == 0 ? x1 : y1, L == 0 ? y1 : y2,
        enc, speech_bf, KRP, Wab, Wa_bv[L], va_W[L], bw[L], pctx, lg, hg, ctr);
  }

  head_kernel<<<2048, 256, 0, stream>>>(y2, m1W, m1b, m2W, m2b, dW, db, (float*)d_out);
  (void)in_sizes; (void)n_in; (void)out_size; (void)ws_size;
}

// Round 5
// 39768.964 us; speedup vs baseline: 2.0044x; 1.6492x over previous
//
#include <hip/hip_runtime.h>
#include <hip/hip_bf16.h>
#include <stdint.h>

#define B  64
#define TD 512
#define TE 1024
#define EE 512
#define UU 256

// ---------- numeric helpers ----------
__device__ __forceinline__ float fexp2(float x){ return __builtin_amdgcn_exp2f(x); }
__device__ __forceinline__ float frcp_(float x){ return __builtin_amdgcn_rcpf(x); }
__device__ __forceinline__ float tanh_fast(float x){
  float e = fexp2(x * 2.885390082f);
  return 1.f - 2.f * frcp_(e + 1.f);
}
__device__ __forceinline__ float sigmoid_fast(float x){
  return frcp_(1.f + fexp2(-1.442695041f * x));
}
__device__ __forceinline__ unsigned short f2bf(float f){
  unsigned int u = __float_as_uint(f);
  u = (u + 0x7fffu + ((u >> 16) & 1u)) >> 16;   // RNE
  return (unsigned short)u;
}
__device__ __forceinline__ float bflo(unsigned int w){ return __uint_as_float(w << 16); }
__device__ __forceinline__ float bfhi(unsigned int w){ return __uint_as_float(w & 0xffff0000u); }

// Cross-XCD comm WITHOUT cache flushes: relaxed system-scope ops lower to
// global_load/store/atomic with sc0 sc1 (bypass L1/L2, coherent at L3) and
// never emit buffer_inv/buffer_wbl2 -> L2 stays hot for speech/KRP.
__device__ __forceinline__ void gstore(float* p, float v){
  __hip_atomic_store(p, v, __ATOMIC_RELAXED, __HIP_MEMORY_SCOPE_SYSTEM);
}
__device__ __forceinline__ float gload(const float* p){
  return __hip_atomic_load(p, __ATOMIC_RELAXED, __HIP_MEMORY_SCOPE_SYSTEM);
}
__device__ __forceinline__ void drain_stores(){
  __atomic_signal_fence(__ATOMIC_SEQ_CST);
  __builtin_amdgcn_s_waitcnt(0);
  __atomic_signal_fence(__ATOMIC_SEQ_CST);
}

// Gate partial GEMV (512-thread WG, 128 output columns) over k-range
// [k0, k0+32*NITER). c = j-chunk (8 of 128 cols), kg = k-group. Lanes
// {l, l+16, l+32, l+48} share c -> 2-step shfl reduce, lane<16 atomics.
template<int NITER>
__device__ __forceinline__ void gate_accum8(const unsigned short* __restrict__ KRP,
    const float* catp, float* zb, int q8, int k0, int tid, int lane){
  const int c = tid & 15, kg = tid >> 4;     // kg in [0,32)
  const uint4* kp = (const uint4*)KRP + ((size_t)q8*1024 + k0 + kg*NITER)*16 + c;
  float a0=0.f,a1=0.f,a2=0.f,a3=0.f,a4=0.f,a5=0.f,a6=0.f,a7=0.f;
  #pragma unroll 4
  for (int i = 0; i < NITER; ++i){
    uint4 w = kp[(size_t)i*16];
    float ck = catp[k0 + kg*NITER + i];
    a0 += ck*bflo(w.x); a1 += ck*bfhi(w.x);
    a2 += ck*bflo(w.y); a3 += ck*bfhi(w.y);
    a4 += ck*bflo(w.z); a5 += ck*bfhi(w.z);
    a6 += ck*bflo(w.w); a7 += ck*bfhi(w.w);
  }
  a0 += __shfl_xor(a0, 16); a1 += __shfl_xor(a1, 16);
  a2 += __shfl_xor(a2, 16); a3 += __shfl_xor(a3, 16);
  a4 += __shfl_xor(a4, 16); a5 += __shfl_xor(a5, 16);
  a6 += __shfl_xor(a6, 16); a7 += __shfl_xor(a7, 16);
  a0 += __shfl_xor(a0, 32); a1 += __shfl_xor(a1, 32);
  a2 += __shfl_xor(a2, 32); a3 += __shfl_xor(a3, 32);
  a4 += __shfl_xor(a4, 32); a5 += __shfl_xor(a5, 32);
  a6 += __shfl_xor(a6, 32); a7 += __shfl_xor(a7, 32);
  if (lane < 16){
    atomicAdd(&zb[c*8+0], a0); atomicAdd(&zb[c*8+1], a1);
    atomicAdd(&zb[c*8+2], a2); atomicAdd(&zb[c*8+3], a3);
    atomicAdd(&zb[c*8+4], a4); atomicAdd(&zb[c*8+5], a5);
    atomicAdd(&zb[c*8+6], a6); atomicAdd(&zb[c*8+7], a7);
  }
}

// ---------- pack kernels ----------
__global__ void pack_bf16v(const float* __restrict__ in, unsigned short* __restrict__ out, int n4){
  int i = blockIdx.x * blockDim.x + threadIdx.x;
  int stride = gridDim.x * blockDim.x;
  for (; i < n4; i += stride){
    float4 v = ((const float4*)in)[i];
    ushort4 o;
    o.x = f2bf(v.x); o.y = f2bf(v.y); o.z = f2bf(v.z); o.w = f2bf(v.w);
    ((ushort4*)out)[i] = o;
  }
}

// KRP[q8][k][jj]: per-WG-contiguous gate weights for 8 WGs/batch. jj in
// [0,128) maps to logical column J = (jj>>5)*256 + q8*32 + (jj&31);
// rows 0..767 = K, 768..1023 = R. Total 8*1024*128 = 1,048,576 elements
// -> grid MUST be 4096 x 256 exactly.
__global__ void pack_KRP(const float* __restrict__ K, const float* __restrict__ R,
                         unsigned short* __restrict__ KRP){
  int idx = blockIdx.x * 256 + threadIdx.x;    // 4096 blocks -> 1M exactly
  int q8 = idx >> 17;
  int k  = (idx >> 7) & 1023;
  int jj = idx & 127;
  int J  = (jj >> 5)*256 + q8*32 + (jj & 31);
  float v = (k < 768) ? K[(size_t)k*1024 + J] : R[(size_t)(k - 768)*1024 + J];
  KRP[idx] = f2bf(v);
}

// ---------- secrets = trans @ emb_W + emb_b : [32768,64]@[64,256] ----------
__global__ __launch_bounds__(256) void emb_gemm(const float* __restrict__ trans,
    const float* __restrict__ W, const float* __restrict__ bias, float* __restrict__ out){
  __shared__ __align__(16) float aT[64*20];
  const int row0 = blockIdx.x * 16;
  const int tid = threadIdx.x;
  {
    int r = tid >> 6, k = tid & 63;
    for (int rr = r; rr < 16; rr += 4)
      aT[k*20 + rr] = trans[(size_t)(row0 + rr)*64 + k];
  }
  __syncthreads();
  const int j = tid;
  float bj = bias[j];
  float acc[16];
  #pragma unroll
  for (int r = 0; r < 16; ++r) acc[r] = bj;
  for (int k = 0; k < 64; ++k){
    float w = W[(size_t)k*UU + j];
    const float4* a4 = (const float4*)(aT + k*20);
    float4 q0 = a4[0], q1 = a4[1], q2 = a4[2], q3 = a4[3];
    acc[0]+=q0.x*w;  acc[1]+=q0.y*w;  acc[2]+=q0.z*w;  acc[3]+=q0.w*w;
    acc[4]+=q1.x*w;  acc[5]+=q1.y*w;  acc[6]+=q1.z*w;  acc[7]+=q1.w*w;
    acc[8]+=q2.x*w;  acc[9]+=q2.y*w;  acc[10]+=q2.z*w; acc[11]+=q2.w*w;
    acc[12]+=q3.x*w; acc[13]+=q3.y*w; acc[14]+=q3.z*w; acc[15]+=q3.w*w;
  }
  #pragma unroll
  for (int r = 0; r < 16; ++r)
    out[(size_t)(row0 + r)*UU + j] = acc[r];
}

// ---------- enc = speech @ Ua + Ua_b, stored bf16 [B][TE][U] ----------
__global__ __launch_bounds__(256) void enc_gemm(const float* __restrict__ speech,
    const float* __restrict__ Ua, const float* __restrict__ Uab,
    unsigned short* __restrict__ enc){
  __shared__ __align__(16) float aT[512*20];
  const int wg = blockIdx.x;
  const int b = wg >> 6, tb = (wg & 63) * 16;
  const int tid = threadIdx.x;
  const float* sp = speech + ((size_t)b*TE + tb)*EE;
  for (int it = 0; it < 32; ++it){
    int idx = tid + 256*it;
    int te = idx >> 9, e = idx & 511;
    aT[e*20 + te] = sp[(size_t)te*EE + e];
  }
  __syncthreads();
  const int j = tid;
  float bj = Uab[j];
  float acc[16];
  #pragma unroll
  for (int r = 0; r < 16; ++r) acc[r] = bj;
  const float* up = Ua + j;
  for (int e = 0; e < 512; ++e){
    float w = up[(size_t)e*UU];
    const float4* a4 = (const float4*)(aT + e*20);
    float4 q0 = a4[0], q1 = a4[1], q2 = a4[2], q3 = a4[3];
    acc[0]+=q0.x*w;  acc[1]+=q0.y*w;  acc[2]+=q0.z*w;  acc[3]+=q0.w*w;
    acc[4]+=q1.x*w;  acc[5]+=q1.y*w;  acc[6]+=q1.z*w;  acc[7]+=q1.w*w;
    acc[8]+=q2.x*w;  acc[9]+=q2.y*w;  acc[10]+=q2.z*w; acc[11]+=q2.w*w;
    acc[12]+=q3.x*w; acc[13]+=q3.y*w; acc[14]+=q3.z*w; acc[15]+=q3.w*w;
  }
  unsigned short* op = enc + ((size_t)b*TE + tb)*UU + j;
  #pragma unroll
  for (int r = 0; r < 16; ++r) op[(size_t)r*UU] = f2bf(acc[r]);
}

// ---------- persistent attention-LSTM scan ----------
// R9 restructure: 512 WGs x 512 threads = 8 WGs/batch (q8 = bid&7,
// b = bid>>3). Same total waves (16/CU) as before, but now each CU hosts
// TWO WGs from DIFFERENT batches (co-resident pair = (bid, bid+256) under
// SE round-robin; b differs by 32): while one batch's WG spins at a
// barrier, the other batch's 8 waves compute. R4 counters showed
// VALUBusy=15.5% with ~85% of step time as idle waits that a 1-WG/CU
// layout can never hide.
// LDS/WG: enc slice 128x264x2 = 67,584 dyn + ~13,056 static = 80.6 KB
// -> exactly 2 WG/CU (160 KB). All 512 WGs resident (required: spin
// barriers). waves_per_eu(4,4) -> <=128 VGPRs, 16 waves/CU schedulable.
// Wab streamed from L2 (co-resident WG hides its latency; reg-residency
// bought ~0 in R8 and costs 32 regs).
__global__ __launch_bounds__(512)
__attribute__((amdgpu_waves_per_eu(4, 4)))
void scan_kernel(
    const float* __restrict__ x_seq, float* __restrict__ y_out,
    const unsigned short* __restrict__ enc, const unsigned short* __restrict__ speech,
    const unsigned short* __restrict__ KRP, const unsigned short* __restrict__ Wab,
    const float* __restrict__ Wa_b, const float* __restrict__ va,
    const float* __restrict__ gate_b,
    float* __restrict__ pctx_g, float* __restrict__ l_g, float* __restrict__ h_g,
    unsigned int* __restrict__ ctr){
  extern __shared__ __align__(16) unsigned short enc_l[];   // [128][264] = 67.6 KB
  __shared__ float2 sva[256];        // (s[u], va[u])
  __shared__ float cat[1024];        // [0,256)=x_t  [256,768)=ctx  [768,1024)=h_{t-1}
  __shared__ float c_lds[32];
  __shared__ float lds_logit4[512];  // [4 u-quarters][128 te]
  __shared__ float p_lds[128];
  __shared__ float lds_pctx[512];
  __shared__ float zbuf[2][128];     // gate accumulators, ping-pong over t
  __shared__ float s_acc[256];
  __shared__ float red[16];
  __shared__ float nmi[2];

  const int tid = threadIdx.x;
  const int wg = blockIdx.x;
  const int b = wg >> 3, q8 = wg & 7;
  const int lane = tid & 63, wave = tid >> 6;
  unsigned int bar = 0;
  unsigned int* cptr = &ctr[b*16];

  // one-time: stage this WG's enc slice (128 te x 256 u bf16) into LDS
  {
    const uint4* ep4 = (const uint4*)(enc + ((size_t)b*TE + q8*128)*UU);
    #pragma unroll
    for (int i = 0; i < 8; ++i){
      int idx = tid + 512*i;                    // 4096 uint4
      int te_l = idx >> 5, ch = idx & 31;
      uint4 v = ep4[(size_t)te_l*32 + ch];
      *(uint4*)(enc_l + (size_t)te_l*264 + ch*8) = v;
    }
  }
  if (tid < 256){ sva[tid] = make_float2(Wa_b[tid], va[tid]); cat[768 + tid] = 0.f; }
  if (tid < 128){ zbuf[0][tid] = 0.f; zbuf[1][tid] = 0.f; }
  if (tid < 32) c_lds[tid] = 0.f;
  if (tid >= 256 && tid < 512)
    cat[tid - 256] = x_seq[((size_t)b*TD + 0)*UU + (tid - 256)];
  __syncthreads();
  // prologue: x-rows gate contribution for t=0
  gate_accum8<8>(KRP, cat, zbuf[0], q8, 0, tid, lane);

  for (int t = 0; t < TD; ++t){
    // ---- loop top: zero scratch, issue x_{t+1} load (held in register) ----
    lds_pctx[tid] = 0.f;
    if (tid < 128) zbuf[(t+1)&1][tid] = 0.f;
    if (tid < 256) s_acc[tid] = 0.f;
    float xnext = 0.f;
    if (t < TD-1 && tid >= 256 && tid < 512)
      xnext = x_seq[((size_t)b*TD + t + 1)*UU + (tid - 256)];
    __syncthreads();

    // ---- P1: attention logits from LDS enc (conflict-free partial stores) ----
    {
      const int g = wave & 1, r = wave >> 1;
      const int te_l = g*64 + lane;             // local te 0..127
      const unsigned short* ep = enc_l + (size_t)te_l*264 + r*64;
      float acc = 0.f;
      #pragma unroll
      for (int c = 0; c < 8; ++c){
        uint4 v = *(const uint4*)(ep + c*8);
        const int ub = r*64 + c*8;
        unsigned int wv[4] = {v.x, v.y, v.z, v.w};
        #pragma unroll
        for (int i = 0; i < 4; ++i){
          float2 s0 = sva[ub + 2*i];
          float2 s1 = sva[ub + 2*i + 1];
          acc += s0.y * tanh_fast(s0.x + bflo(wv[i]));
          acc += s1.y * tanh_fast(s1.x + bfhi(wv[i]));
        }
      }
      lds_logit4[r*128 + te_l] = acc;           // unique (r,te_l) per thread
    }
    __syncthreads();

    // ---- P2: p = exp(logit), wave partial sums ----
    if (tid < 128){
      float lg = lds_logit4[tid] + lds_logit4[128 + tid]
               + lds_logit4[256 + tid] + lds_logit4[384 + tid];
      float p = fexp2(lg * 1.442695041f);
      p_lds[tid] = p;
      float s = p;
      #pragma unroll
      for (int o = 32; o > 0; o >>= 1) s += __shfl_xor(s, o);
      if (lane == 0) red[wave] = s;
    }
    __syncthreads();

    // ---- P3: partial ctx = sum_te p[te]*speech[te][:]  (uint4 stream) ----
    {
      const int c = tid & 63, tg = tid >> 6;    // e-chunk (8 e), te-group (16 te)
      const uint4* sp4 = (const uint4*)speech + ((size_t)b*TE + q8*128 + tg*16)*64 + c;
      float a0=0.f,a1=0.f,a2=0.f,a3=0.f,a4=0.f,a5=0.f,a6=0.f,a7=0.f;
      #pragma unroll 4
      for (int i = 0; i < 16; ++i){
        uint4 w = sp4[(size_t)i*64];
        float p = p_lds[tg*16 + i];
        a0 += p*bflo(w.x); a1 += p*bfhi(w.x);
        a2 += p*bflo(w.y); a3 += p*bfhi(w.y);
        a4 += p*bflo(w.z); a5 += p*bfhi(w.z);
        a6 += p*bflo(w.w); a7 += p*bfhi(w.w);
      }
      atomicAdd(&lds_pctx[c*8+0], a0); atomicAdd(&lds_pctx[c*8+1], a1);
      atomicAdd(&lds_pctx[c*8+2], a2); atomicAdd(&lds_pctx[c*8+3], a3);
      atomicAdd(&lds_pctx[c*8+4], a4); atomicAdd(&lds_pctx[c*8+5], a5);
      atomicAdd(&lds_pctx[c*8+6], a6); atomicAdd(&lds_pctx[c*8+7], a7);
    }
    __syncthreads();
    gstore(&pctx_g[((size_t)(b*8 + q8))*512 + tid], lds_pctx[tid]);
    if (tid == 0)  gstore(&l_g[b*8 + q8], red[0] + red[1]);
    drain_stores();
    __syncthreads();
    // ---- barrier A signal (poll deferred: window work hides it) ----
    bar += 8;
    if (tid == 0)
      __hip_atomic_fetch_add(cptr, 1u, __ATOMIC_RELAXED, __HIP_MEMORY_SCOPE_SYSTEM);

    // ---- A-window 1: gate h-rows (k 768..1023), needs only h_{t-1} ----
    gate_accum8<8>(KRP, cat, zbuf[t&1], q8, 768, tid, lane);

    // ---- A-window 2: y_{t-1} = whatever_norm(h_{t-1}) (off critical path;
    //      all WGs reduce redundantly, each writes its own 32-wide slice) ----
    if (t > 0){
      if (tid < 256){
        float hv = cat[768 + tid];
        float s1 = hv, s2 = hv*hv;
        #pragma unroll
        for (int o = 32; o > 0; o >>= 1){ s1 += __shfl_xor(s1, o); s2 += __shfl_xor(s2, o); }
        if (lane == 0){ red[wave*2] = s1; red[wave*2 + 1] = s2; }
      }
      __syncthreads();
      if (tid == 0){
        float m  = (red[0] + red[2] + red[4] + red[6]) * (1.f/256.f);
        float ms = (red[1] + red[3] + red[5] + red[7]) * (1.f/256.f);
        nmi[0] = m;
        nmi[1] = rsqrtf(ms - m*m + 1e-4f);
      }
      __syncthreads();
      if (tid < 32)
        y_out[((size_t)b*TD + (t-1))*UU + q8*32 + tid] =
            (cat[768 + q8*32 + tid] - nmi[0]) * nmi[1];
    }

    // ---- barrier A poll ----
    if (tid == 0){
      while (__hip_atomic_load(cptr, __ATOMIC_RELAXED, __HIP_MEMORY_SCOPE_SYSTEM) < bar)
        __builtin_amdgcn_s_sleep(2);
    }
    __syncthreads();

    // ---- merge ctx (8 partials) ----
    {
      float lsum = 0.f;
      #pragma unroll
      for (int k = 0; k < 8; ++k) lsum += gload(&l_g[b*8 + k]);
      float linv = frcp_(lsum);
      float s0 = 0.f;
      #pragma unroll
      for (int k = 0; k < 8; ++k)
        s0 += gload(&pctx_g[((size_t)(b*8 + k))*512 + tid]);
      cat[256 + tid] = s0 * linv;
    }
    __syncthreads();

    // ---- gate ctx-rows (k 256..767): 16-iter uint4 stream ----
    gate_accum8<16>(KRP, cat, zbuf[t&1], q8, 256, tid, lane);
    __syncthreads();

    // ---- LSTM pointwise (keras i,f,g,o), export h slice ----
    if (tid < 32){
      const int jj = q8*32 + tid;
      const float* zb = zbuf[t&1];
      float zi = zb[tid]      + gate_b[jj];
      float zf = zb[32 + tid] + gate_b[256 + jj];
      float zg = zb[64 + tid] + gate_b[512 + jj];
      float zo = zb[96 + tid] + gate_b[768 + jj];
      float cn = sigmoid_fast(zf) * c_lds[tid] + sigmoid_fast(zi) * tanh_fast(zg);
      c_lds[tid] = cn;
      gstore(&h_g[(size_t)b*UU + jj], sigmoid_fast(zo) * tanh_fast(cn));
    }
    // park x_{t+1} (loaded at loop top) into cat[0..256)
    if (t < TD-1 && tid >= 256 && tid < 512) cat[tid - 256] = xnext;
    drain_stores();
    __syncthreads();
    // ---- barrier B signal (poll deferred: x-rows of t+1 hide it) ----
    bar += 8;
    if (tid == 0)
      __hip_atomic_fetch_add(cptr, 1u, __ATOMIC_RELAXED, __HIP_MEMORY_SCOPE_SYSTEM);

    // ---- B-window: gate x-rows for t+1 (k 0..255), needs only x_{t+1} ----
    if (t < TD-1)
      gate_accum8<8>(KRP, cat, zbuf[(t+1)&1], q8, 0, tid, lane);

    // ---- barrier B poll ----
    if (tid == 0){
      while (__hip_atomic_load(cptr, __ATOMIC_RELAXED, __HIP_MEMORY_SCOPE_SYSTEM) < bar)
        __builtin_amdgcn_s_sleep(2);
    }
    __syncthreads();

    if (tid < 256) cat[768 + tid] = gload(&h_g[(size_t)b*UU + tid]);
    __syncthreads();

    // ---- s_{t+1} = h_t @ Wa + Wa_b (L2 stream; co-resident WG hides it) ----
    if (t < TD - 1){
      {
        const int c = tid & 31, kg = tid >> 5;  // u-chunk (8 u), kg in [0,16)
        const uint4* wp = (const uint4*)Wab + (size_t)(kg*16)*32 + c;
        float a0=0.f,a1=0.f,a2=0.f,a3=0.f,a4=0.f,a5=0.f,a6=0.f,a7=0.f;
        #pragma unroll 4
        for (int i = 0; i < 16; ++i){
          uint4 w = wp[(size_t)i*32];
          float hk = cat[768 + kg*16 + i];
          a0 += hk*bflo(w.x); a1 += hk*bfhi(w.x);
          a2 += hk*bflo(w.y); a3 += hk*bfhi(w.y);
          a4 += hk*bflo(w.z); a5 += hk*bfhi(w.z);
          a6 += hk*bflo(w.w); a7 += hk*bfhi(w.w);
        }
        a0 += __shfl_xor(a0, 32); a1 += __shfl_xor(a1, 32);
        a2 += __shfl_xor(a2, 32); a3 += __shfl_xor(a3, 32);
        a4 += __shfl_xor(a4, 32); a5 += __shfl_xor(a5, 32);
        a6 += __shfl_xor(a6, 32); a7 += __shfl_xor(a7, 32);
        if (lane < 32){
          atomicAdd(&s_acc[c*8+0], a0); atomicAdd(&s_acc[c*8+1], a1);
          atomicAdd(&s_acc[c*8+2], a2); atomicAdd(&s_acc[c*8+3], a3);
          atomicAdd(&s_acc[c*8+4], a4); atomicAdd(&s_acc[c*8+5], a5);
          atomicAdd(&s_acc[c*8+6], a6); atomicAdd(&s_acc[c*8+7], a7);
        }
      }
      __syncthreads();
      if (tid < 256) sva[tid].x = Wa_b[tid] + s_acc[tid];
    }
    __syncthreads();
  }

  // ---- epilogue: y_{TD-1} = whatever_norm(h_{TD-1}) ----
  {
    if (tid < 256){
      float hv = cat[768 + tid];
      float s1 = hv, s2 = hv*hv;
      #pragma unroll
      for (int o = 32; o > 0; o >>= 1){ s1 += __shfl_xor(s1, o); s2 += __shfl_xor(s2, o); }
      if (lane == 0){ red[wave*2] = s1; red[wave*2 + 1] = s2; }
    }
    __syncthreads();
    if (tid == 0){
      float m  = (red[0] + red[2] + red[4] + red[6]) * (1.f/256.f);
      float ms = (red[1] + red[3] + red[5] + red[7]) * (1.f/256.f);
      nmi[0] = m;
      nmi[1] = rsqrtf(ms - m*m + 1e-4f);
    }
    __syncthreads();
    if (tid < 32)
      y_out[((size_t)b*TD + (TD-1))*UU + q8*32 + tid] =
          (cat[768 + q8*32 + tid] - nmi[0]) * nmi[1];
  }
}

// ---------- head: norm(norm(y2@m1+b)@m2+b)@dW+db -> softmax ----------
__global__ __launch_bounds__(256) void head_kernel(const float* __restrict__ y2,
    const float* __restrict__ m1W, const float* __restrict__ m1b,
    const float* __restrict__ m2W, const float* __restrict__ m2b,
    const float* __restrict__ dW, const float* __restrict__ db,
    float* __restrict__ out){
  __shared__ __align__(16) float aT[256*20];
  __shared__ float t_lds[16*256];
  __shared__ float zl[16*64];
  __shared__ float mi[32];
  const int row0 = blockIdx.x * 16;
  const int tid = threadIdx.x;
  for (int it = 0; it < 16; ++it){
    int idx = tid + 256*it;
    int r = idx >> 8, k = idx & 255;
    aT[k*20 + r] = y2[(size_t)(row0 + r)*UU + k];
  }
  __syncthreads();

  #pragma unroll 1
  for (int pass = 0; pass < 2; ++pass){
    const float* Wp = pass ? m2W : m1W;
    const float* bp = pass ? m2b : m1b;
    const int j = tid;
    float bj = bp[j];
    float acc[16];
    #pragma unroll
    for (int r = 0; r < 16; ++r) acc[r] = bj;
    for (int k = 0; k < 256; ++k){
      float w = Wp[(size_t)k*UU + j];
      const float4* a4 = (const float4*)(aT + k*20);
      float4 q0 = a4[0], q1 = a4[1], q2 = a4[2], q3 = a4[3];
      acc[0]+=q0.x*w;  acc[1]+=q0.y*w;  acc[2]+=q0.z*w;  acc[3]+=q0.w*w;
      acc[4]+=q1.x*w;  acc[5]+=q1.y*w;  acc[6]+=q1.z*w;  acc[7]+=q1.w*w;
      acc[8]+=q2.x*w;  acc[9]+=q2.y*w;  acc[10]+=q2.z*w; acc[11]+=q2.w*w;
      acc[12]+=q3.x*w; acc[13]+=q3.y*w; acc[14]+=q3.z*w; acc[15]+=q3.w*w;
    }
    #pragma unroll
    for (int r = 0; r < 16; ++r) t_lds[r*256 + j] = acc[r];
    __syncthreads();
    {
      int r = tid >> 4, sg = tid & 15;
      float s1 = 0.f, s2 = 0.f;
      for (int c = 0; c < 16; ++c){
        float v = t_lds[r*256 + sg*16 + c];
        s1 += v; s2 += v*v;
      }
      for (int o = 1; o < 16; o <<= 1){ s1 += __shfl_xor(s1, o); s2 += __shfl_xor(s2, o); }
      if (sg == 0){
        float m = s1 * (1.f/256.f);
        float vv = s2 * (1.f/256.f) - m*m;
        mi[r*2] = m; mi[r*2+1] = rsqrtf(vv + 1e-4f);
      }
    }
    __syncthreads();
    {
      const int j2 = tid;
      #pragma unroll
      for (int r = 0; r < 16; ++r)
        aT[j2*20 + r] = (t_lds[r*256 + j2] - mi[r*2]) * mi[r*2+1];
    }
    __syncthreads();
  }

  for (int i = tid; i < 1024; i += 256) zl[i] = 0.f;
  __syncthreads();
  {
    const int j = tid & 63, kq = tid >> 6;
    float acc[16];
    #pragma unroll
    for (int r = 0; r < 16; ++r) acc[r] = 0.f;
    for (int k = 0; k < 64; ++k){
      float w = dW[(size_t)(kq*64 + k)*64 + j];
      const float4* a4 = (const float4*)(aT + (kq*64 + k)*20);
      float4 q0 = a4[0], q1 = a4[1], q2 = a4[2], q3 = a4[3];
      acc[0]+=q0.x*w;  acc[1]+=q0.y*w;  acc[2]+=q0.z*w;  acc[3]+=q0.w*w;
      acc[4]+=q1.x*w;  acc[5]+=q1.y*w;  acc[6]+=q1.z*w;  acc[7]+=q1.w*w;
      acc[8]+=q2.x*w;  acc[9]+=q2.y*w;  acc[10]+=q2.z*w; acc[11]+=q2.w*w;
      acc[12]+=q3.x*w; acc[13]+=q3.y*w; acc[14]+=q3.z*w; acc[15]+=q3.w*w;
    }
    #pragma unroll
    for (int r = 0; r < 16; ++r) atomicAdd(&zl[r*64 + j], acc[r]);
  }
  __syncthreads();
  if (tid < 16){
    const int r = tid;
    float mx = -1e30f;
    for (int j = 0; j < 64; ++j){ float v = zl[r*64 + j] + db[j]; zl[r*64 + j] = v; mx = fmaxf(mx, v); }
    float s = 0.f;
    for (int j = 0; j < 64; ++j){ float e = fexp2((zl[r*64 + j] - mx) * 1.442695041f); zl[r*64 + j] = e; s += e; }
    mi[r] = frcp_(s);
  }
  __syncthreads();
  for (int it = 0; it < 4; ++it){
    int idx = tid + 256*it;
    int r = idx >> 6, j = idx & 63;
    out[(size_t)(row0 + r)*64 + j] = zl[r*64 + j] * mi[r];
  }
}

// ---------- workspace layout (bytes) ----------
#define OFF_SPEECH 0u
#define OFF_ENC    67108864u
#define OFF_KR     100663296u
#define OFF_WA     102760448u
#define OFF_X1     102891520u
#define OFF_Y1     136445952u
#define OFF_PCTX   170000384u   // 64*8*512*4 = 1 MB
#define OFF_L      171048960u   // 64*8*4 = 2 KB
#define OFF_H      171051008u   // 64 KB
#define OFF_CTR    171116544u   // 4 KB -> total ~171.1 MB

#define DYN_LDS    67584    // 128 rows x 264 ushorts

extern "C" void kernel_launch(void* const* d_in, const int* in_sizes, int n_in,
                              void* d_out, int out_size, void* d_ws, size_t ws_size,
                              hipStream_t stream){
  const float* trans  = (const float*)d_in[0];
  const float* speech = (const float*)d_in[1];
  const float* emb_W  = (const float*)d_in[2];
  const float* emb_b  = (const float*)d_in[3];
  const float* Ua_W[2]  = {(const float*)d_in[4],  (const float*)d_in[13]};
  const float* Ua_b[2]  = {(const float*)d_in[5],  (const float*)d_in[14]};
  const float* Wa_W[2]  = {(const float*)d_in[6],  (const float*)d_in[15]};
  const float* Wa_bv[2] = {(const float*)d_in[7],  (const float*)d_in[16]};
  const float* va_W[2]  = {(const float*)d_in[8],  (const float*)d_in[17]};
  // d_in[9]/d_in[18] = va_b: constant logit shift, softmax-invariant, dropped exactly.
  const float* Kw[2]    = {(const float*)d_in[10], (const float*)d_in[19]};
  const float* Rw[2]    = {(const float*)d_in[11], (const float*)d_in[20]};
  const float* bw[2]    = {(const float*)d_in[12], (const float*)d_in[21]};
  const float* m1W = (const float*)d_in[22];
  const float* m1b = (const float*)d_in[23];
  const float* m2W = (const float*)d_in[24];
  const float* m2b = (const float*)d_in[25];
  const float* dW  = (const float*)d_in[26];
  const float* db  = (const float*)d_in[27];

  char* ws = (char*)d_ws;
  unsigned short* speech_bf = (unsigned short*)(ws + OFF_SPEECH);
  unsigned short* enc  = (unsigned short*)(ws + OFF_ENC);
  unsigned short* KRP  = (unsigned short*)(ws + OFF_KR);
  unsigned short* Wab  = (unsigned short*)(ws + OFF_WA);
  float* x1   = (float*)(ws + OFF_X1);
  float* y1   = (float*)(ws + OFF_Y1);
  float* pctx = (float*)(ws + OFF_PCTX);
  float* lg   = (float*)(ws + OFF_L);
  float* hg   = (float*)(ws + OFF_H);
  unsigned int* ctr = (unsigned int*)(ws + OFF_CTR);
  float* y2 = x1;   // x1 dead after scan1 consumes it

  hipFuncSetAttribute((const void*)scan_kernel,
                      hipFuncAttributeMaxDynamicSharedMemorySize, DYN_LDS);

  hipMemsetAsync(ctr, 0, 4096, stream);
  pack_bf16v<<<4096, 256, 0, stream>>>(speech, speech_bf, B*TE*EE/4);
  emb_gemm<<<2048, 256, 0, stream>>>(trans, emb_W, emb_b, x1);

  for (int L = 0; L < 2; ++L){
    enc_gemm<<<4096, 256, 0, stream>>>(speech, Ua_W[L], Ua_b[L], enc);
    pack_KRP<<<4096, 256, 0, stream>>>(Kw[L], Rw[L], KRP);
    pack_bf16v<<<64, 256, 0, stream>>>(Wa_W[L], Wab, UU*UU/4);
    if (L == 1) hipMemsetAsync(ctr, 0, 4096, stream);
    scan_kernel<<<512, 512, DYN_LDS, stream>>>(L == 0 ? x1 : y1, L == 0 ? y1 : y2,
        enc, speech_bf, KRP, Wab, Wa_bv[L], va_W[L], bw[L], pctx, lg, hg, ctr);
  }

  head_kernel<<<2048, 256, 0, stream>>>(y2, m1W, m1b, m2W, m2b, dW, db, (float*)d_out);
  (void)in_sizes; (void)n_in; (void)out_size; (void)ws_size;
}